// Round 1
// baseline (22112.614 us; speedup 1.0000x reference)
//
#include <hip/hip_runtime.h>
#include <hip/hip_bf16.h>

// Problem: B=4, S=2048, D=1024, INNER=2048, STATE=512.
// out = out_proj(scan(in_proj(hidden)));  scan folded via Wcomb = Wsp @ Wup.

#define S_LEN 2048
#define NBATCH 4
#define DMODEL 1024
#define INNER_N 2048
#define NSTATE 512
#define NBLK 256

typedef __attribute__((ext_vector_type(4))) float f32x4;
typedef __attribute__((ext_vector_type(8))) short bf16x8;

__device__ __forceinline__ unsigned short f2bf(float f) {
  unsigned u = __builtin_bit_cast(unsigned, f);
  u += 0x7FFFu + ((u >> 16) & 1u);
  return (unsigned short)(u >> 16);
}
__device__ __forceinline__ float bflo(unsigned u) { return __builtin_bit_cast(float, (unsigned)(u << 16)); }
__device__ __forceinline__ float bfhi(unsigned u) { return __builtin_bit_cast(float, u & 0xFFFF0000u); }
__device__ __forceinline__ float b2f(unsigned short s) { return __builtin_bit_cast(float, (unsigned)s << 16); }

__device__ __forceinline__ float wave_sum64(float v) {
#pragma unroll
  for (int m = 32; m >= 1; m >>= 1) v += __shfl_xor(v, m, 64);
  return v;
}

// ---------------- fp32 -> bf16 convert (8 elems/thread) ----------------
__global__ void conv_f32_bf16(const float* __restrict__ in, unsigned short* __restrict__ out, int n8) {
  int g = blockIdx.x * 256 + threadIdx.x;
  if (g >= n8) return;
  const float4* p = (const float4*)in + 2 * (size_t)g;
  float4 a = p[0], b = p[1];
  uint4 o;
  o.x = (unsigned)f2bf(a.x) | ((unsigned)f2bf(a.y) << 16);
  o.y = (unsigned)f2bf(a.z) | ((unsigned)f2bf(a.w) << 16);
  o.z = (unsigned)f2bf(b.x) | ((unsigned)f2bf(b.y) << 16);
  o.w = (unsigned)f2bf(b.z) | ((unsigned)f2bf(b.w) << 16);
  ((uint4*)out)[g] = o;
}

// ---------------- Wup [512][2048] -> WupT bf16 [2048][512] ----------------
__global__ void transpose_wup(const float* __restrict__ in, unsigned short* __restrict__ out) {
  int g = blockIdx.x * 256 + threadIdx.x; // over 2048*512
  int i = g >> 9, k = g & 511;
  out[g] = f2bf(in[(size_t)k * 2048 + i]);
}

// ---------------- b_comb[j] = b_sp[j] + sum_k Wsp[j,k]*b_up[k] ----------------
__global__ void bcomb_kernel(const float* __restrict__ wsp, const float* __restrict__ bsp,
                             const float* __restrict__ bup, float* __restrict__ bcomb) {
  int wv = (blockIdx.x * 256 + threadIdx.x) >> 6;
  int lane = threadIdx.x & 63;
  if (wv >= 4096) return;
  float s = 0.f;
  for (int k = lane; k < 512; k += 64) s += wsp[(size_t)wv * 512 + k] * bup[k];
  s = wave_sum64(s);
  if (lane == 0) bcomb[wv] = s + bsp[wv];
}

// ---------------- sp0[b][j] = b_sp[j] + sum_k state0[b,k]*Wsp[j,k] ----------------
__global__ void sp0_kernel(const float* __restrict__ wsp, const float* __restrict__ bsp,
                           const float* __restrict__ state0, float* __restrict__ sp0) {
  int wv = (blockIdx.x * 256 + threadIdx.x) >> 6;
  int lane = threadIdx.x & 63;
  if (wv >= 4096) return;
  float acc[NBATCH] = {0.f, 0.f, 0.f, 0.f};
  for (int k = lane; k < 512; k += 64) {
    float w = wsp[(size_t)wv * 512 + k];
#pragma unroll
    for (int bb = 0; bb < NBATCH; ++bb) acc[bb] += state0[bb * 512 + k] * w;
  }
#pragma unroll
  for (int bb = 0; bb < NBATCH; ++bb) {
    acc[bb] = wave_sum64(acc[bb]);
  }
  if (lane == 0) {
    float b = bsp[wv];
#pragma unroll
    for (int bb = 0; bb < NBATCH; ++bb) sp0[bb * 4096 + wv] = acc[bb] + b;
  }
}

// ---------------- final_state[b][j] = b_up[j] + sum_i mixed[2047,b,i]*Wup[j,i] ----------------
__global__ void final_state_kernel(const float* __restrict__ wup, const float* __restrict__ bup,
                                   const unsigned short* __restrict__ mixedg, float* __restrict__ dst) {
  int wv = (blockIdx.x * 256 + threadIdx.x) >> 6;
  int lane = threadIdx.x & 63;
  if (wv >= 512) return;
  float acc[NBATCH] = {0.f, 0.f, 0.f, 0.f};
  for (int i = lane; i < 2048; i += 64) {
    float w = wup[(size_t)wv * 2048 + i];
#pragma unroll
    for (int bb = 0; bb < NBATCH; ++bb)
      acc[bb] += b2f(mixedg[((size_t)2047 * 4 + bb) * 2048 + i]) * w;
  }
#pragma unroll
  for (int bb = 0; bb < NBATCH; ++bb) acc[bb] = wave_sum64(acc[bb]);
  if (lane == 0) {
    float b = bup[wv];
#pragma unroll
    for (int bb = 0; bb < NBATCH; ++bb) dst[bb * 512 + wv] = acc[bb] + b;
  }
}

// ---------------- bf16 BT-GEMM: C[M,N] = A[M,K] @ B[N,K]^T (+bias) ----------------
// MODE 0: bf16 out + bias; MODE 1: bf16 out, no bias; MODE 2: fp32 out, bias,
// row remap m=s*4+b -> out[b][s][n] (S=2048, N=1024 hardcoded for out_proj).
template <int MODE>
__global__ __launch_bounds__(256) void gemm_bt(
    const unsigned short* __restrict__ A, const unsigned short* __restrict__ B,
    unsigned short* __restrict__ Cbf, float* __restrict__ Cf32,
    const float* __restrict__ bias, int M, int N, int K) {
  const int tm = blockIdx.x * 128, tn = blockIdx.y * 128;
  __shared__ __align__(16) unsigned short At[128][72];
  __shared__ __align__(16) unsigned short Bt[128][72];
  const int tid = threadIdx.x, lane = tid & 63, w = tid >> 6;
  const int wm = (w >> 1) * 64, wn = (w & 1) * 64;
  f32x4 acc[4][4];
#pragma unroll
  for (int a = 0; a < 4; ++a)
#pragma unroll
    for (int b = 0; b < 4; ++b) acc[a][b] = (f32x4)0.f;

  for (int k0 = 0; k0 < K; k0 += 64) {
#pragma unroll
    for (int it = 0; it < 4; ++it) {
      int c = tid + it * 256;
      int r = c >> 3, kp = (c & 7) * 8;
      *(uint4*)&At[r][kp] = *(const uint4*)&A[(size_t)(tm + r) * K + k0 + kp];
      *(uint4*)&Bt[r][kp] = *(const uint4*)&B[(size_t)(tn + r) * K + k0 + kp];
    }
    __syncthreads();
#pragma unroll
    for (int kk = 0; kk < 2; ++kk) {
      bf16x8 af[4], bfr[4];
#pragma unroll
      for (int fm = 0; fm < 4; ++fm)
        af[fm] = *(const bf16x8*)&At[wm + fm * 16 + (lane & 15)][(kk << 5) + ((lane >> 4) << 3)];
#pragma unroll
      for (int fn = 0; fn < 4; ++fn)
        bfr[fn] = *(const bf16x8*)&Bt[wn + fn * 16 + (lane & 15)][(kk << 5) + ((lane >> 4) << 3)];
#pragma unroll
      for (int fm = 0; fm < 4; ++fm)
#pragma unroll
        for (int fn = 0; fn < 4; ++fn)
          acc[fm][fn] = __builtin_amdgcn_mfma_f32_16x16x32_bf16(af[fm], bfr[fn], acc[fm][fn], 0, 0, 0);
    }
    __syncthreads();
  }
  // epilogue
  float bv[4];
#pragma unroll
  for (int fn = 0; fn < 4; ++fn) {
    if constexpr (MODE != 1) bv[fn] = bias[tn + wn + fn * 16 + (lane & 15)];
    else bv[fn] = 0.f;
  }
#pragma unroll
  for (int fm = 0; fm < 4; ++fm)
#pragma unroll
    for (int fn = 0; fn < 4; ++fn)
#pragma unroll
      for (int r = 0; r < 4; ++r) {
        int row = tm + wm + fm * 16 + ((lane >> 4) << 2) + r;
        int col = tn + wn + fn * 16 + (lane & 15);
        float v = acc[fm][fn][r] + bv[fn];
        if constexpr (MODE == 2) {
          Cf32[(size_t)(((row & 3) << 11) + (row >> 2)) * 1024 + col] = v;
        } else {
          Cbf[(size_t)row * N + col] = f2bf(v);
        }
      }
}

// ---------------- persistent scan kernel ----------------
// 256 blocks x 256 threads, 1 block/CU. Block b owns INNER slice [8b, 8b+8).
// LDS holds its 16 rows of Wcomb (u rows j=I0..I0+8, g rows 2048+I0..) in bf16.
// Per step: sp = b_comb + mixed_{t-1} @ Wcomb_slice^T, nonlinearity, publish
// mixed slice to LLC (agent-scope stores), flag barrier (all-poll-all).
__global__ __launch_bounds__(256, 1) void scan_kernel(
    const unsigned short* __restrict__ wcombg,  // [4096][2048] bf16
    const float* __restrict__ bcombg,           // [4096]
    const float* __restrict__ sp0g,             // [4][4096]
    const unsigned short* __restrict__ projg,   // [8192][6144] bf16, m=b*2048+s
    unsigned short* __restrict__ mixedg,        // [2048][4][2048] bf16
    unsigned int* __restrict__ flags)           // [256], zeroed before launch
{
  __shared__ __align__(16) unsigned short wcomb_lds[16][2048];  // 64 KB
  __shared__ __align__(16) unsigned short mixed_lds[4][2048];   // 16 KB
  __shared__ __align__(16) float spbuf[16][4];
  __shared__ __align__(16) float bcomb_lds[16];
  __shared__ __align__(16) unsigned short tok_lds[3][4][8];
  __shared__ __align__(16) unsigned short nlbuf[4][8];

  const int tid = threadIdx.x, bid = blockIdx.x;
  const int lane = tid & 63, jq = tid >> 6;
  const int I0 = bid * 8;

  // stage Wcomb slice
  for (int c = tid; c < 16 * 256; c += 256) {
    int r = c >> 8, kp = (c & 255) << 3;
    int gj = (r < 8) ? (I0 + r) : (2048 + I0 + r - 8);
    *(uint4*)&wcomb_lds[r][kp] = *(const uint4*)&wcombg[((size_t)gj << 11) + kp];
  }
  if (tid < 16) bcomb_lds[tid] = bcombg[(tid < 8) ? (I0 + tid) : (2048 + I0 + tid - 8)];
  __syncthreads();

#pragma unroll 1
  for (int t = 0; t < S_LEN; ++t) {
    // stage this step's token slices (u,g,v) and previous mixed
    if (tid < 12) {
      int wp = tid >> 2, bb = tid & 3;
      *(uint4*)&tok_lds[wp][bb][0] =
          *(const uint4*)&projg[(size_t)(bb * 2048 + t) * 6144 + wp * 2048 + I0];
    }
    if (t > 0) {
      const uint4* src = (const uint4*)(mixedg + ((size_t)(t - 1) << 13));
      for (int c = tid; c < 1024; c += 256) ((uint4*)mixed_lds)[c] = src[c];
    }
    __syncthreads();

    if (t > 0) {
      float acc[4][4];  // [q][bb]
#pragma unroll
      for (int q = 0; q < 4; ++q)
#pragma unroll
        for (int bb = 0; bb < 4; ++bb) acc[q][bb] = 0.f;

#pragma unroll
      for (int s8 = 0; s8 < 4; ++s8) {
        const int i0 = (s8 << 9) + (lane << 3);
        uint4 mx[4], wv4[4];
#pragma unroll
        for (int bb = 0; bb < 4; ++bb) mx[bb] = *(const uint4*)&mixed_lds[bb][i0];
#pragma unroll
        for (int q = 0; q < 4; ++q) wv4[q] = *(const uint4*)&wcomb_lds[(jq << 2) + q][i0];
#pragma unroll
        for (int d = 0; d < 4; ++d) {
          float mlo[4], mhi[4];
#pragma unroll
          for (int bb = 0; bb < 4; ++bb) {
            unsigned u = ((const unsigned*)&mx[bb])[d];
            mlo[bb] = bflo(u); mhi[bb] = bfhi(u);
          }
#pragma unroll
          for (int q = 0; q < 4; ++q) {
            unsigned u = ((const unsigned*)&wv4[q])[d];
            float wlo = bflo(u), whi = bfhi(u);
#pragma unroll
            for (int bb = 0; bb < 4; ++bb) acc[q][bb] += wlo * mlo[bb] + whi * mhi[bb];
          }
        }
      }
      // reduce across the wave (lanes partition i)
#pragma unroll
      for (int q = 0; q < 4; ++q)
#pragma unroll
        for (int bb = 0; bb < 4; ++bb) acc[q][bb] = wave_sum64(acc[q][bb]);
      if (lane == 0) {
#pragma unroll
        for (int q = 0; q < 4; ++q) {
          f32x4 v; v[0] = acc[q][0]; v[1] = acc[q][1]; v[2] = acc[q][2]; v[3] = acc[q][3];
          *(f32x4*)&spbuf[(jq << 2) + q][0] = v;
        }
      }
    }
    __syncthreads();

    if (tid < 32) {
      const int i = tid & 7, bb = tid >> 3;
      float su, sg;
      if (t == 0) {
        su = sp0g[bb * 4096 + I0 + i];
        sg = sp0g[bb * 4096 + 2048 + I0 + i];
      } else {
        su = spbuf[i][bb] + bcomb_lds[i];
        sg = spbuf[8 + i][bb] + bcomb_lds[8 + i];
      }
      float tu = b2f(tok_lds[0][bb][i]);
      float tg = b2f(tok_lds[1][bb][i]);
      float tv = b2f(tok_lds[2][bb][i]);
      float cand = tanhf(tu + su);
      float gate = 1.0f / (1.0f + expf(-(tg + sg)));
      float mix = gate * cand + (1.0f - gate) * tanhf(tv);
      nlbuf[bb][i] = f2bf(mix);
    }
    __syncthreads();
    if (tid < 16) {  // publish slice: agent-scope (LLC) stores, 4B packed
      const int bb = tid >> 2, g = tid & 3;
      unsigned lo = nlbuf[bb][2 * g], hi = nlbuf[bb][2 * g + 1];
      unsigned* dst = (unsigned*)(mixedg + ((size_t)t * 4 + bb) * 2048 + I0);
      __hip_atomic_store(dst + g, lo | (hi << 16), __ATOMIC_RELAXED, __HIP_MEMORY_SCOPE_AGENT);
    }

    if (t < S_LEN - 1) {
      __syncthreads();  // drains each thread's stores (vmcnt) before flag
      if (tid == 0)
        __hip_atomic_store(&flags[bid], (unsigned)(t + 1), __ATOMIC_RELEASE, __HIP_MEMORY_SCOPE_AGENT);
      const unsigned tgt = (unsigned)(t + 1);
      while (__hip_atomic_load(&flags[tid], __ATOMIC_RELAXED, __HIP_MEMORY_SCOPE_AGENT) < tgt)
        __builtin_amdgcn_s_sleep(2);
      __syncthreads();
    }
  }
}

extern "C" void kernel_launch(void* const* d_in, const int* in_sizes, int n_in,
                              void* d_out, int out_size, void* d_ws, size_t ws_size,
                              hipStream_t stream) {
  (void)in_sizes; (void)n_in; (void)out_size; (void)ws_size;
  const float* hidden = (const float*)d_in[0];
  const float* state0 = (const float*)d_in[1];
  const float* w_in   = (const float*)d_in[2];
  const float* b_in   = (const float*)d_in[3];
  const float* w_sp   = (const float*)d_in[4];
  const float* b_sp   = (const float*)d_in[5];
  const float* w_out  = (const float*)d_in[6];
  const float* b_out  = (const float*)d_in[7];
  const float* w_up   = (const float*)d_in[8];
  const float* b_up   = (const float*)d_in[9];
  float* out = (float*)d_out;
  char* ws = (char*)d_ws;

  size_t o = 0;
  auto take = [&](size_t b) { size_t p = o; o += (b + 255) & ~(size_t)255; return p; };
  unsigned* flags        = (unsigned*)(ws + take(NBLK * 4));
  float* sp0p            = (float*)(ws + take((size_t)4 * 4096 * 4));
  float* bcombp          = (float*)(ws + take((size_t)4096 * 4));
  unsigned short* hbf    = (unsigned short*)(ws + take((size_t)8192 * 1024 * 2));
  unsigned short* winbf  = (unsigned short*)(ws + take((size_t)6144 * 1024 * 2));
  unsigned short* wspbf  = (unsigned short*)(ws + take((size_t)4096 * 512 * 2));
  unsigned short* wupTbf = (unsigned short*)(ws + take((size_t)2048 * 512 * 2));
  unsigned short* woutbf = (unsigned short*)(ws + take((size_t)1024 * 2048 * 2));
  unsigned short* wcombbf= (unsigned short*)(ws + take((size_t)4096 * 2048 * 2));
  unsigned short* projbf = (unsigned short*)(ws + take((size_t)8192 * 6144 * 2));
  unsigned short* mixbf  = (unsigned short*)(ws + take((size_t)8192 * 2048 * 2));

  hipMemsetAsync(flags, 0, NBLK * 4, stream);

  conv_f32_bf16<<<4096, 256, 0, stream>>>(hidden, hbf, 1048576);
  conv_f32_bf16<<<3072, 256, 0, stream>>>(w_in, winbf, 786432);
  conv_f32_bf16<<<1024, 256, 0, stream>>>(w_sp, wspbf, 262144);
  conv_f32_bf16<<<1024, 256, 0, stream>>>(w_out, woutbf, 262144);
  transpose_wup<<<4096, 256, 0, stream>>>(w_up, wupTbf);

  // projected = hidden @ in_proj_w^T + b_in   [8192, 6144] bf16
  gemm_bt<0><<<dim3(64, 48), 256, 0, stream>>>(hbf, winbf, projbf, nullptr, b_in, 8192, 6144, 1024);
  // Wcomb = Wsp @ Wup   [4096, 2048] bf16  (B = Wup^T as [2048,512])
  gemm_bt<1><<<dim3(32, 16), 256, 0, stream>>>(wspbf, wupTbf, wcombbf, nullptr, nullptr, 4096, 2048, 512);

  bcomb_kernel<<<1024, 256, 0, stream>>>(w_sp, b_sp, b_up, bcombp);
  sp0_kernel<<<1024, 256, 0, stream>>>(w_sp, b_sp, state0, sp0p);

  {
    const unsigned short* a0 = wcombbf;
    const float* a1 = bcombp;
    const float* a2 = sp0p;
    const unsigned short* a3 = projbf;
    unsigned short* a4 = mixbf;
    unsigned* a5 = flags;
    void* args[] = {&a0, &a1, &a2, &a3, &a4, &a5};
    hipLaunchCooperativeKernel((const void*)scan_kernel, dim3(NBLK), dim3(256), args, 0, stream);
  }

  // out = mixed @ out_proj_w^T + b_out  -> fp32, remapped to [B,S,D]
  gemm_bt<2><<<dim3(64, 8), 256, 0, stream>>>(mixbf, woutbf, nullptr, out, b_out, 8192, 1024, 2048);
  final_state_kernel<<<128, 256, 0, stream>>>(w_up, b_up, mixbf, out + (size_t)8192 * 1024);
}

// Round 4
// 18295.824 us; speedup vs baseline: 1.2086x; 1.2086x over previous
//
#include <hip/hip_runtime.h>
#include <hip/hip_bf16.h>

// Problem: B=4, S=2048, D=1024, INNER=2048, STATE=512.
// out = out_proj(scan(in_proj(hidden)));  scan folded via Wcomb = Wsp @ Wup.
// Round 4 = round-1 kernel (known good) with ONE change: publish via
// returning atomic swaps + vmcnt drain + RELAXED flag (no release/buffer_wbl2).

#define S_LEN 2048
#define NBATCH 4
#define NBLK 256

typedef __attribute__((ext_vector_type(4))) float f32x4;
typedef __attribute__((ext_vector_type(8))) short bf16x8;

__device__ __forceinline__ unsigned short f2bf(float f) {
  unsigned u = __builtin_bit_cast(unsigned, f);
  u += 0x7FFFu + ((u >> 16) & 1u);
  return (unsigned short)(u >> 16);
}
__device__ __forceinline__ float bflo(unsigned u) { return __builtin_bit_cast(float, (unsigned)(u << 16)); }
__device__ __forceinline__ float bfhi(unsigned u) { return __builtin_bit_cast(float, u & 0xFFFF0000u); }
__device__ __forceinline__ float b2f(unsigned short s) { return __builtin_bit_cast(float, (unsigned)s << 16); }

__device__ __forceinline__ float wave_sum64(float v) {
#pragma unroll
  for (int m = 32; m >= 1; m >>= 1) v += __shfl_xor(v, m, 64);
  return v;
}

#define WAIT_VM0() asm volatile("s_waitcnt vmcnt(0)" ::: "memory")

// ---------------- fp32 -> bf16 convert (8 elems/thread) ----------------
__global__ void conv_f32_bf16(const float* __restrict__ in, unsigned short* __restrict__ out, int n8) {
  int g = blockIdx.x * 256 + threadIdx.x;
  if (g >= n8) return;
  const float4* p = (const float4*)in + 2 * (size_t)g;
  float4 a = p[0], b = p[1];
  uint4 o;
  o.x = (unsigned)f2bf(a.x) | ((unsigned)f2bf(a.y) << 16);
  o.y = (unsigned)f2bf(a.z) | ((unsigned)f2bf(a.w) << 16);
  o.z = (unsigned)f2bf(b.x) | ((unsigned)f2bf(b.y) << 16);
  o.w = (unsigned)f2bf(b.z) | ((unsigned)f2bf(b.w) << 16);
  ((uint4*)out)[g] = o;
}

// ---------------- Wup [512][2048] -> WupT bf16 [2048][512] ----------------
__global__ void transpose_wup(const float* __restrict__ in, unsigned short* __restrict__ out) {
  int g = blockIdx.x * 256 + threadIdx.x; // over 2048*512
  int i = g >> 9, k = g & 511;
  out[g] = f2bf(in[(size_t)k * 2048 + i]);
}

// ---------------- b_comb[j] = b_sp[j] + sum_k Wsp[j,k]*b_up[k] ----------------
__global__ void bcomb_kernel(const float* __restrict__ wsp, const float* __restrict__ bsp,
                             const float* __restrict__ bup, float* __restrict__ bcomb) {
  int wv = (blockIdx.x * 256 + threadIdx.x) >> 6;
  int lane = threadIdx.x & 63;
  if (wv >= 4096) return;
  float s = 0.f;
  for (int k = lane; k < 512; k += 64) s += wsp[(size_t)wv * 512 + k] * bup[k];
  s = wave_sum64(s);
  if (lane == 0) bcomb[wv] = s + bsp[wv];
}

// ---------------- sp0[b][j] = b_sp[j] + sum_k state0[b,k]*Wsp[j,k] ----------------
__global__ void sp0_kernel(const float* __restrict__ wsp, const float* __restrict__ bsp,
                           const float* __restrict__ state0, float* __restrict__ sp0) {
  int wv = (blockIdx.x * 256 + threadIdx.x) >> 6;
  int lane = threadIdx.x & 63;
  if (wv >= 4096) return;
  float acc[NBATCH] = {0.f, 0.f, 0.f, 0.f};
  for (int k = lane; k < 512; k += 64) {
    float w = wsp[(size_t)wv * 512 + k];
#pragma unroll
    for (int bb = 0; bb < NBATCH; ++bb) acc[bb] += state0[bb * 512 + k] * w;
  }
#pragma unroll
  for (int bb = 0; bb < NBATCH; ++bb) acc[bb] = wave_sum64(acc[bb]);
  if (lane == 0) {
    float b = bsp[wv];
#pragma unroll
    for (int bb = 0; bb < NBATCH; ++bb) sp0[bb * 4096 + wv] = acc[bb] + b;
  }
}

// ---------------- final_state[b][j] = b_up[j] + sum_i mixed[2047,b,i]*Wup[j,i] ----------------
__global__ void final_state_kernel(const float* __restrict__ wup, const float* __restrict__ bup,
                                   const unsigned short* __restrict__ mixedg, float* __restrict__ dst) {
  int wv = (blockIdx.x * 256 + threadIdx.x) >> 6;
  int lane = threadIdx.x & 63;
  if (wv >= 512) return;
  float acc[NBATCH] = {0.f, 0.f, 0.f, 0.f};
  for (int i = lane; i < 2048; i += 64) {
    float w = wup[(size_t)wv * 2048 + i];
#pragma unroll
    for (int bb = 0; bb < NBATCH; ++bb)
      acc[bb] += b2f(mixedg[((size_t)2047 * 4 + bb) * 2048 + i]) * w;
  }
#pragma unroll
  for (int bb = 0; bb < NBATCH; ++bb) acc[bb] = wave_sum64(acc[bb]);
  if (lane == 0) {
    float b = bup[wv];
#pragma unroll
    for (int bb = 0; bb < NBATCH; ++bb) dst[bb * 512 + wv] = acc[bb] + b;
  }
}

// ---------------- bf16 BT-GEMM: C[M,N] = A[M,K] @ B[N,K]^T (+bias) ----------------
// MODE 0: bf16 out + bias; MODE 1: bf16 out, no bias; MODE 2: fp32 out, bias,
// row remap m=s*4+b -> out[b][s][n] (S=2048, N=1024 hardcoded for out_proj).
template <int MODE>
__global__ __launch_bounds__(256) void gemm_bt(
    const unsigned short* __restrict__ A, const unsigned short* __restrict__ B,
    unsigned short* __restrict__ Cbf, float* __restrict__ Cf32,
    const float* __restrict__ bias, int M, int N, int K) {
  const int tm = blockIdx.x * 128, tn = blockIdx.y * 128;
  __shared__ __align__(16) unsigned short At[128][72];
  __shared__ __align__(16) unsigned short Bt[128][72];
  const int tid = threadIdx.x, lane = tid & 63, w = tid >> 6;
  const int wm = (w >> 1) * 64, wn = (w & 1) * 64;
  f32x4 acc[4][4];
#pragma unroll
  for (int a = 0; a < 4; ++a)
#pragma unroll
    for (int b = 0; b < 4; ++b) acc[a][b] = (f32x4)0.f;

  for (int k0 = 0; k0 < K; k0 += 64) {
#pragma unroll
    for (int it = 0; it < 4; ++it) {
      int c = tid + it * 256;
      int r = c >> 3, kp = (c & 7) * 8;
      *(uint4*)&At[r][kp] = *(const uint4*)&A[(size_t)(tm + r) * K + k0 + kp];
      *(uint4*)&Bt[r][kp] = *(const uint4*)&B[(size_t)(tn + r) * K + k0 + kp];
    }
    __syncthreads();
#pragma unroll
    for (int kk = 0; kk < 2; ++kk) {
      bf16x8 af[4], bfr[4];
#pragma unroll
      for (int fm = 0; fm < 4; ++fm)
        af[fm] = *(const bf16x8*)&At[wm + fm * 16 + (lane & 15)][(kk << 5) + ((lane >> 4) << 3)];
#pragma unroll
      for (int fn = 0; fn < 4; ++fn)
        bfr[fn] = *(const bf16x8*)&Bt[wn + fn * 16 + (lane & 15)][(kk << 5) + ((lane >> 4) << 3)];
#pragma unroll
      for (int fm = 0; fm < 4; ++fm)
#pragma unroll
        for (int fn = 0; fn < 4; ++fn)
          acc[fm][fn] = __builtin_amdgcn_mfma_f32_16x16x32_bf16(af[fm], bfr[fn], acc[fm][fn], 0, 0, 0);
    }
    __syncthreads();
  }
  // epilogue
  float bv[4];
#pragma unroll
  for (int fn = 0; fn < 4; ++fn) {
    if constexpr (MODE != 1) bv[fn] = bias[tn + wn + fn * 16 + (lane & 15)];
    else bv[fn] = 0.f;
  }
#pragma unroll
  for (int fm = 0; fm < 4; ++fm)
#pragma unroll
    for (int fn = 0; fn < 4; ++fn)
#pragma unroll
      for (int r = 0; r < 4; ++r) {
        int row = tm + wm + fm * 16 + ((lane >> 4) << 2) + r;
        int col = tn + wn + fn * 16 + (lane & 15);
        float v = acc[fm][fn][r] + bv[fn];
        if constexpr (MODE == 2) {
          Cf32[(size_t)(((row & 3) << 11) + (row >> 2)) * 1024 + col] = v;
        } else {
          Cbf[(size_t)row * N + col] = f2bf(v);
        }
      }
}

// ---------------- persistent scan kernel (round-1 structure) ----------------
// 256 blocks x 256 threads, 1 block/CU. Block b owns INNER slice [8b, 8b+8).
// Per step: sp = b_comb + mixed_{t-1} @ Wcomb_slice^T, nonlinearity, publish
// mixed slice via RETURNING atomic swaps (vmcnt ack = performed at LLC),
// wave-0 vmcnt drain, RELAXED flag store, all-poll-all barrier.
__global__ __launch_bounds__(256, 1) void scan_kernel(
    const unsigned short* __restrict__ wcombg,  // [4096][2048] bf16
    const float* __restrict__ bcombg,           // [4096]
    const float* __restrict__ sp0g,             // [4][4096]
    const unsigned short* __restrict__ projg,   // [8192][6144] bf16, m=b*2048+s
    unsigned short* __restrict__ mixedg,        // [2048][4][2048] bf16
    unsigned int* __restrict__ flags)           // [256], zeroed before launch
{
  __shared__ __align__(16) unsigned short wcomb_lds[16][2048];  // 64 KB
  __shared__ __align__(16) unsigned short mixed_lds[4][2048];   // 16 KB
  __shared__ __align__(16) float spbuf[16][4];
  __shared__ __align__(16) float bcomb_lds[16];
  __shared__ __align__(16) unsigned short tok_lds[3][4][8];
  __shared__ __align__(16) unsigned short nlbuf[4][8];

  const int tid = threadIdx.x, bid = blockIdx.x;
  const int lane = tid & 63, jq = tid >> 6;
  const int I0 = bid * 8;

  // stage Wcomb slice
  for (int c = tid; c < 16 * 256; c += 256) {
    int r = c >> 8, kp = (c & 255) << 3;
    int gj = (r < 8) ? (I0 + r) : (2048 + I0 + r - 8);
    *(uint4*)&wcomb_lds[r][kp] = *(const uint4*)&wcombg[((size_t)gj << 11) + kp];
  }
  if (tid < 16) bcomb_lds[tid] = bcombg[(tid < 8) ? (I0 + tid) : (2048 + I0 + tid - 8)];
  __syncthreads();

#pragma unroll 1
  for (int t = 0; t < S_LEN; ++t) {
    // stage this step's token slices (u,g,v) and previous mixed
    if (tid < 12) {
      int wp = tid >> 2, bb = tid & 3;
      *(uint4*)&tok_lds[wp][bb][0] =
          *(const uint4*)&projg[(size_t)(bb * 2048 + t) * 6144 + wp * 2048 + I0];
    }
    if (t > 0) {
      const uint4* src = (const uint4*)(mixedg + ((size_t)(t - 1) << 13));
      for (int c = tid; c < 1024; c += 256) ((uint4*)mixed_lds)[c] = src[c];
    }
    __syncthreads();

    if (t > 0) {
      float acc[4][4];  // [q][bb]
#pragma unroll
      for (int q = 0; q < 4; ++q)
#pragma unroll
        for (int bb = 0; bb < 4; ++bb) acc[q][bb] = 0.f;

#pragma unroll
      for (int s8 = 0; s8 < 4; ++s8) {
        const int i0 = (s8 << 9) + (lane << 3);
        uint4 mx[4], wv4[4];
#pragma unroll
        for (int bb = 0; bb < 4; ++bb) mx[bb] = *(const uint4*)&mixed_lds[bb][i0];
#pragma unroll
        for (int q = 0; q < 4; ++q) wv4[q] = *(const uint4*)&wcomb_lds[(jq << 2) + q][i0];
#pragma unroll
        for (int d = 0; d < 4; ++d) {
          float mlo[4], mhi[4];
#pragma unroll
          for (int bb = 0; bb < 4; ++bb) {
            unsigned u = ((const unsigned*)&mx[bb])[d];
            mlo[bb] = bflo(u); mhi[bb] = bfhi(u);
          }
#pragma unroll
          for (int q = 0; q < 4; ++q) {
            unsigned u = ((const unsigned*)&wv4[q])[d];
            float wlo = bflo(u), whi = bfhi(u);
#pragma unroll
            for (int bb = 0; bb < 4; ++bb) acc[q][bb] += wlo * mlo[bb] + whi * mhi[bb];
          }
        }
      }
      // reduce across the wave (lanes partition i)
#pragma unroll
      for (int q = 0; q < 4; ++q)
#pragma unroll
        for (int bb = 0; bb < 4; ++bb) acc[q][bb] = wave_sum64(acc[q][bb]);
      if (lane == 0) {
#pragma unroll
        for (int q = 0; q < 4; ++q) {
          f32x4 v; v[0] = acc[q][0]; v[1] = acc[q][1]; v[2] = acc[q][2]; v[3] = acc[q][3];
          *(f32x4*)&spbuf[(jq << 2) + q][0] = v;
        }
      }
    }
    __syncthreads();

    if (tid < 32) {
      const int i = tid & 7, bb = tid >> 3;
      float su, sg;
      if (t == 0) {
        su = sp0g[bb * 4096 + I0 + i];
        sg = sp0g[bb * 4096 + 2048 + I0 + i];
      } else {
        su = spbuf[i][bb] + bcomb_lds[i];
        sg = spbuf[8 + i][bb] + bcomb_lds[8 + i];
      }
      float tu = b2f(tok_lds[0][bb][i]);
      float tg = b2f(tok_lds[1][bb][i]);
      float tv = b2f(tok_lds[2][bb][i]);
      float cand = tanhf(tu + su);
      float gate = 1.0f / (1.0f + expf(-(tg + sg)));
      float mix = gate * cand + (1.0f - gate) * tanhf(tv);
      nlbuf[bb][i] = f2bf(mix);
    }
    __syncthreads();
    if (tid < 16) {  // publish slice via RETURNING atomic swap (performs at LLC)
      const int bb = tid >> 2, g = tid & 3;
      unsigned lo = nlbuf[bb][2 * g], hi = nlbuf[bb][2 * g + 1];
      unsigned* dst = (unsigned*)(mixedg + ((size_t)t * 4 + bb) * 2048 + I0);
      unsigned old = __hip_atomic_exchange(dst + g, lo | (hi << 16),
                                           __ATOMIC_RELAXED, __HIP_MEMORY_SCOPE_AGENT);
      asm volatile("" :: "v"(old));  // keep returning form live (sc0)
    }

    if (t < S_LEN - 1) {
      if (tid < 64) WAIT_VM0();  // wave 0 drains its 16 swaps: data performed at LLC
      if (tid == 0)
        __hip_atomic_store(&flags[bid], (unsigned)(t + 1), __ATOMIC_RELAXED, __HIP_MEMORY_SCOPE_AGENT);
      const unsigned tgt = (unsigned)(t + 1);
      while (__hip_atomic_load(&flags[tid], __ATOMIC_RELAXED, __HIP_MEMORY_SCOPE_AGENT) < tgt)
        __builtin_amdgcn_s_sleep(2);
      __syncthreads();
    }
  }
}

extern "C" void kernel_launch(void* const* d_in, const int* in_sizes, int n_in,
                              void* d_out, int out_size, void* d_ws, size_t ws_size,
                              hipStream_t stream) {
  (void)in_sizes; (void)n_in; (void)out_size; (void)ws_size;
  const float* hidden = (const float*)d_in[0];
  const float* state0 = (const float*)d_in[1];
  const float* w_in   = (const float*)d_in[2];
  const float* b_in   = (const float*)d_in[3];
  const float* w_sp   = (const float*)d_in[4];
  const float* b_sp   = (const float*)d_in[5];
  const float* w_out  = (const float*)d_in[6];
  const float* b_out  = (const float*)d_in[7];
  const float* w_up   = (const float*)d_in[8];
  const float* b_up   = (const float*)d_in[9];
  float* out = (float*)d_out;
  char* ws = (char*)d_ws;

  size_t o = 0;
  auto take = [&](size_t b) { size_t p = o; o += (b + 255) & ~(size_t)255; return p; };
  unsigned* flags        = (unsigned*)(ws + take(NBLK * 4));
  float* sp0p            = (float*)(ws + take((size_t)4 * 4096 * 4));
  float* bcombp          = (float*)(ws + take((size_t)4096 * 4));
  unsigned short* hbf    = (unsigned short*)(ws + take((size_t)8192 * 1024 * 2));
  unsigned short* winbf  = (unsigned short*)(ws + take((size_t)6144 * 1024 * 2));
  unsigned short* wspbf  = (unsigned short*)(ws + take((size_t)4096 * 512 * 2));
  unsigned short* wupTbf = (unsigned short*)(ws + take((size_t)2048 * 512 * 2));
  unsigned short* woutbf = (unsigned short*)(ws + take((size_t)1024 * 2048 * 2));
  unsigned short* wcombbf= (unsigned short*)(ws + take((size_t)4096 * 2048 * 2));
  unsigned short* projbf = (unsigned short*)(ws + take((size_t)8192 * 6144 * 2));
  unsigned short* mixbf  = (unsigned short*)(ws + take((size_t)8192 * 2048 * 2));

  hipMemsetAsync(flags, 0, NBLK * 4, stream);

  conv_f32_bf16<<<4096, 256, 0, stream>>>(hidden, hbf, 1048576);
  conv_f32_bf16<<<3072, 256, 0, stream>>>(w_in, winbf, 786432);
  conv_f32_bf16<<<1024, 256, 0, stream>>>(w_sp, wspbf, 262144);
  conv_f32_bf16<<<1024, 256, 0, stream>>>(w_out, woutbf, 262144);
  transpose_wup<<<4096, 256, 0, stream>>>(w_up, wupTbf);

  // projected = hidden @ in_proj_w^T + b_in   [8192, 6144] bf16
  gemm_bt<0><<<dim3(64, 48), 256, 0, stream>>>(hbf, winbf, projbf, nullptr, b_in, 8192, 6144, 1024);
  // Wcomb = Wsp @ Wup   [4096, 2048] bf16  (B = Wup^T as [2048,512])
  gemm_bt<1><<<dim3(32, 16), 256, 0, stream>>>(wspbf, wupTbf, wcombbf, nullptr, nullptr, 4096, 2048, 512);

  bcomb_kernel<<<1024, 256, 0, stream>>>(w_sp, b_sp, b_up, bcombp);
  sp0_kernel<<<1024, 256, 0, stream>>>(w_sp, b_sp, state0, sp0p);

  {
    const unsigned short* a0 = wcombbf;
    const float* a1 = bcombp;
    const float* a2 = sp0p;
    const unsigned short* a3 = projbf;
    unsigned short* a4 = mixbf;
    unsigned* a5 = flags;
    void* args[] = {&a0, &a1, &a2, &a3, &a4, &a5};
    hipLaunchCooperativeKernel((const void*)scan_kernel, dim3(NBLK), dim3(256), args, 0, stream);
  }

  // out = mixed @ out_proj_w^T + b_out  -> fp32, remapped to [B,S,D]
  gemm_bt<2><<<dim3(64, 8), 256, 0, stream>>>(mixbf, woutbf, nullptr, out, b_out, 8192, 1024, 2048);
  final_state_kernel<<<128, 256, 0, stream>>>(w_up, b_up, mixbf, out + (size_t)8192 * 1024);
}

// Round 5
// 18196.800 us; speedup vs baseline: 1.2152x; 1.0054x over previous
//
#include <hip/hip_runtime.h>
#include <hip/hip_bf16.h>

// Problem: B=4, S=2048, D=1024, INNER=2048, STATE=512.
// out = out_proj(scan(in_proj(hidden)));  scan folded via Wcomb = Wsp @ Wup.
// Round 5 = round-4 kernel with ONE sync-mechanism change: all-poll-all flag
// array -> single cumulative counter (atomicAdd per block, wave0 polls).

#define S_LEN 2048
#define NBATCH 4
#define NBLK 256

typedef __attribute__((ext_vector_type(4))) float f32x4;
typedef __attribute__((ext_vector_type(8))) short bf16x8;

__device__ __forceinline__ unsigned short f2bf(float f) {
  unsigned u = __builtin_bit_cast(unsigned, f);
  u += 0x7FFFu + ((u >> 16) & 1u);
  return (unsigned short)(u >> 16);
}
__device__ __forceinline__ float bflo(unsigned u) { return __builtin_bit_cast(float, (unsigned)(u << 16)); }
__device__ __forceinline__ float bfhi(unsigned u) { return __builtin_bit_cast(float, u & 0xFFFF0000u); }
__device__ __forceinline__ float b2f(unsigned short s) { return __builtin_bit_cast(float, (unsigned)s << 16); }

__device__ __forceinline__ float wave_sum64(float v) {
#pragma unroll
  for (int m = 32; m >= 1; m >>= 1) v += __shfl_xor(v, m, 64);
  return v;
}

#define WAIT_VM0()   asm volatile("s_waitcnt vmcnt(0)" ::: "memory")
#define WAIT_LGKM0() asm volatile("s_waitcnt lgkmcnt(0)" ::: "memory")

// ---------------- fp32 -> bf16 convert (8 elems/thread) ----------------
__global__ void conv_f32_bf16(const float* __restrict__ in, unsigned short* __restrict__ out, int n8) {
  int g = blockIdx.x * 256 + threadIdx.x;
  if (g >= n8) return;
  const float4* p = (const float4*)in + 2 * (size_t)g;
  float4 a = p[0], b = p[1];
  uint4 o;
  o.x = (unsigned)f2bf(a.x) | ((unsigned)f2bf(a.y) << 16);
  o.y = (unsigned)f2bf(a.z) | ((unsigned)f2bf(a.w) << 16);
  o.z = (unsigned)f2bf(b.x) | ((unsigned)f2bf(b.y) << 16);
  o.w = (unsigned)f2bf(b.z) | ((unsigned)f2bf(b.w) << 16);
  ((uint4*)out)[g] = o;
}

// ---------------- Wup [512][2048] -> WupT bf16 [2048][512] ----------------
__global__ void transpose_wup(const float* __restrict__ in, unsigned short* __restrict__ out) {
  int g = blockIdx.x * 256 + threadIdx.x; // over 2048*512
  int i = g >> 9, k = g & 511;
  out[g] = f2bf(in[(size_t)k * 2048 + i]);
}

// ---------------- b_comb[j] = b_sp[j] + sum_k Wsp[j,k]*b_up[k] ----------------
__global__ void bcomb_kernel(const float* __restrict__ wsp, const float* __restrict__ bsp,
                             const float* __restrict__ bup, float* __restrict__ bcomb) {
  int wv = (blockIdx.x * 256 + threadIdx.x) >> 6;
  int lane = threadIdx.x & 63;
  if (wv >= 4096) return;
  float s = 0.f;
  for (int k = lane; k < 512; k += 64) s += wsp[(size_t)wv * 512 + k] * bup[k];
  s = wave_sum64(s);
  if (lane == 0) bcomb[wv] = s + bsp[wv];
}

// ---------------- sp0[b][j] = b_sp[j] + sum_k state0[b,k]*Wsp[j,k] ----------------
__global__ void sp0_kernel(const float* __restrict__ wsp, const float* __restrict__ bsp,
                           const float* __restrict__ state0, float* __restrict__ sp0) {
  int wv = (blockIdx.x * 256 + threadIdx.x) >> 6;
  int lane = threadIdx.x & 63;
  if (wv >= 4096) return;
  float acc[NBATCH] = {0.f, 0.f, 0.f, 0.f};
  for (int k = lane; k < 512; k += 64) {
    float w = wsp[(size_t)wv * 512 + k];
#pragma unroll
    for (int bb = 0; bb < NBATCH; ++bb) acc[bb] += state0[bb * 512 + k] * w;
  }
#pragma unroll
  for (int bb = 0; bb < NBATCH; ++bb) acc[bb] = wave_sum64(acc[bb]);
  if (lane == 0) {
    float b = bsp[wv];
#pragma unroll
    for (int bb = 0; bb < NBATCH; ++bb) sp0[bb * 4096 + wv] = acc[bb] + b;
  }
}

// ---------------- final_state[b][j] = b_up[j] + sum_i mixed[2047,b,i]*Wup[j,i] ----------------
__global__ void final_state_kernel(const float* __restrict__ wup, const float* __restrict__ bup,
                                   const unsigned short* __restrict__ mixedg, float* __restrict__ dst) {
  int wv = (blockIdx.x * 256 + threadIdx.x) >> 6;
  int lane = threadIdx.x & 63;
  if (wv >= 512) return;
  float acc[NBATCH] = {0.f, 0.f, 0.f, 0.f};
  for (int i = lane; i < 2048; i += 64) {
    float w = wup[(size_t)wv * 2048 + i];
#pragma unroll
    for (int bb = 0; bb < NBATCH; ++bb)
      acc[bb] += b2f(mixedg[((size_t)2047 * 4 + bb) * 2048 + i]) * w;
  }
#pragma unroll
  for (int bb = 0; bb < NBATCH; ++bb) acc[bb] = wave_sum64(acc[bb]);
  if (lane == 0) {
    float b = bup[wv];
#pragma unroll
    for (int bb = 0; bb < NBATCH; ++bb) dst[bb * 512 + wv] = acc[bb] + b;
  }
}

// ---------------- bf16 BT-GEMM: C[M,N] = A[M,K] @ B[N,K]^T (+bias) ----------------
// MODE 0: bf16 out + bias; MODE 1: bf16 out, no bias; MODE 2: fp32 out, bias,
// row remap m=s*4+b -> out[b][s][n] (S=2048, N=1024 hardcoded for out_proj).
template <int MODE>
__global__ __launch_bounds__(256) void gemm_bt(
    const unsigned short* __restrict__ A, const unsigned short* __restrict__ B,
    unsigned short* __restrict__ Cbf, float* __restrict__ Cf32,
    const float* __restrict__ bias, int M, int N, int K) {
  const int tm = blockIdx.x * 128, tn = blockIdx.y * 128;
  __shared__ __align__(16) unsigned short At[128][72];
  __shared__ __align__(16) unsigned short Bt[128][72];
  const int tid = threadIdx.x, lane = tid & 63, w = tid >> 6;
  const int wm = (w >> 1) * 64, wn = (w & 1) * 64;
  f32x4 acc[4][4];
#pragma unroll
  for (int a = 0; a < 4; ++a)
#pragma unroll
    for (int b = 0; b < 4; ++b) acc[a][b] = (f32x4)0.f;

  for (int k0 = 0; k0 < K; k0 += 64) {
#pragma unroll
    for (int it = 0; it < 4; ++it) {
      int c = tid + it * 256;
      int r = c >> 3, kp = (c & 7) * 8;
      *(uint4*)&At[r][kp] = *(const uint4*)&A[(size_t)(tm + r) * K + k0 + kp];
      *(uint4*)&Bt[r][kp] = *(const uint4*)&B[(size_t)(tn + r) * K + k0 + kp];
    }
    __syncthreads();
#pragma unroll
    for (int kk = 0; kk < 2; ++kk) {
      bf16x8 af[4], bfr[4];
#pragma unroll
      for (int fm = 0; fm < 4; ++fm)
        af[fm] = *(const bf16x8*)&At[wm + fm * 16 + (lane & 15)][(kk << 5) + ((lane >> 4) << 3)];
#pragma unroll
      for (int fn = 0; fn < 4; ++fn)
        bfr[fn] = *(const bf16x8*)&Bt[wn + fn * 16 + (lane & 15)][(kk << 5) + ((lane >> 4) << 3)];
#pragma unroll
      for (int fm = 0; fm < 4; ++fm)
#pragma unroll
        for (int fn = 0; fn < 4; ++fn)
          acc[fm][fn] = __builtin_amdgcn_mfma_f32_16x16x32_bf16(af[fm], bfr[fn], acc[fm][fn], 0, 0, 0);
    }
    __syncthreads();
  }
  // epilogue
  float bv[4];
#pragma unroll
  for (int fn = 0; fn < 4; ++fn) {
    if constexpr (MODE != 1) bv[fn] = bias[tn + wn + fn * 16 + (lane & 15)];
    else bv[fn] = 0.f;
  }
#pragma unroll
  for (int fm = 0; fm < 4; ++fm)
#pragma unroll
    for (int fn = 0; fn < 4; ++fn)
#pragma unroll
      for (int r = 0; r < 4; ++r) {
        int row = tm + wm + fm * 16 + ((lane >> 4) << 2) + r;
        int col = tn + wn + fn * 16 + (lane & 15);
        float v = acc[fm][fn][r] + bv[fn];
        if constexpr (MODE == 2) {
          Cf32[(size_t)(((row & 3) << 11) + (row >> 2)) * 1024 + col] = v;
        } else {
          Cbf[(size_t)row * N + col] = f2bf(v);
        }
      }
}

// ---------------- persistent scan kernel ----------------
// 256 blocks x 256 threads, 1 block/CU. Block b owns INNER slice [8b, 8b+8).
// Per step: sp = b_comb + mixed_{t-1} @ Wcomb_slice^T, nonlinearity, publish
// mixed slice via RETURNING atomic swaps (vmcnt ack = performed at LLC),
// wave-0 vmcnt drain, then ONE atomicAdd to a cumulative counter; wave0 polls
// the single counter (coalesced same-address reads), __syncthreads releases.
__global__ __launch_bounds__(256, 1) void scan_kernel(
    const unsigned short* __restrict__ wcombg,  // [4096][2048] bf16
    const float* __restrict__ bcombg,           // [4096]
    const float* __restrict__ sp0g,             // [4][4096]
    const unsigned short* __restrict__ projg,   // [8192][6144] bf16, m=b*2048+s
    unsigned short* __restrict__ mixedg,        // [2048][4][2048] bf16
    unsigned int* __restrict__ cnt)             // [1], zeroed before launch
{
  __shared__ __align__(16) unsigned short wcomb_lds[16][2048];  // 64 KB
  __shared__ __align__(16) unsigned short mixed_lds[4][2048];   // 16 KB
  __shared__ __align__(16) float spbuf[16][4];
  __shared__ __align__(16) float bcomb_lds[16];
  __shared__ __align__(16) unsigned short tok_lds[3][4][8];
  __shared__ __align__(16) unsigned short nlbuf[4][8];

  const int tid = threadIdx.x, bid = blockIdx.x;
  const int lane = tid & 63, jq = tid >> 6;
  const int I0 = bid * 8;

  // stage Wcomb slice
  for (int c = tid; c < 16 * 256; c += 256) {
    int r = c >> 8, kp = (c & 255) << 3;
    int gj = (r < 8) ? (I0 + r) : (2048 + I0 + r - 8);
    *(uint4*)&wcomb_lds[r][kp] = *(const uint4*)&wcombg[((size_t)gj << 11) + kp];
  }
  if (tid < 16) bcomb_lds[tid] = bcombg[(tid < 8) ? (I0 + tid) : (2048 + I0 + tid - 8)];
  __syncthreads();

#pragma unroll 1
  for (int t = 0; t < S_LEN; ++t) {
    // stage this step's token slices (u,g,v) and previous mixed
    if (tid < 12) {
      int wp = tid >> 2, bb = tid & 3;
      *(uint4*)&tok_lds[wp][bb][0] =
          *(const uint4*)&projg[(size_t)(bb * 2048 + t) * 6144 + wp * 2048 + I0];
    }
    if (t > 0) {
      const uint4* src = (const uint4*)(mixedg + ((size_t)(t - 1) << 13));
      for (int c = tid; c < 1024; c += 256) ((uint4*)mixed_lds)[c] = src[c];
    }
    __syncthreads();

    if (t > 0) {
      float acc[4][4];  // [q][bb]
#pragma unroll
      for (int q = 0; q < 4; ++q)
#pragma unroll
        for (int bb = 0; bb < 4; ++bb) acc[q][bb] = 0.f;

#pragma unroll
      for (int s8 = 0; s8 < 4; ++s8) {
        const int i0 = (s8 << 9) + (lane << 3);
        uint4 mx[4], wv4[4];
#pragma unroll
        for (int bb = 0; bb < 4; ++bb) mx[bb] = *(const uint4*)&mixed_lds[bb][i0];
#pragma unroll
        for (int q = 0; q < 4; ++q) wv4[q] = *(const uint4*)&wcomb_lds[(jq << 2) + q][i0];
#pragma unroll
        for (int d = 0; d < 4; ++d) {
          float mlo[4], mhi[4];
#pragma unroll
          for (int bb = 0; bb < 4; ++bb) {
            unsigned u = ((const unsigned*)&mx[bb])[d];
            mlo[bb] = bflo(u); mhi[bb] = bfhi(u);
          }
#pragma unroll
          for (int q = 0; q < 4; ++q) {
            unsigned u = ((const unsigned*)&wv4[q])[d];
            float wlo = bflo(u), whi = bfhi(u);
#pragma unroll
            for (int bb = 0; bb < 4; ++bb) acc[q][bb] += wlo * mlo[bb] + whi * mhi[bb];
          }
        }
      }
      // reduce across the wave (lanes partition i)
#pragma unroll
      for (int q = 0; q < 4; ++q)
#pragma unroll
        for (int bb = 0; bb < 4; ++bb) acc[q][bb] = wave_sum64(acc[q][bb]);
      if (lane == 0) {
#pragma unroll
        for (int q = 0; q < 4; ++q) {
          f32x4 v; v[0] = acc[q][0]; v[1] = acc[q][1]; v[2] = acc[q][2]; v[3] = acc[q][3];
          *(f32x4*)&spbuf[(jq << 2) + q][0] = v;
        }
      }
    }
    __syncthreads();  // spbuf ready (cross-wave)

    // ---- nonlinearity + publish: wave 0 only (same-wave LDS ordering) ----
    if (jq == 0) {
      if (tid < 32) {
        const int i = tid & 7, bb = tid >> 3;
        float su, sg;
        if (t == 0) {
          su = sp0g[bb * 4096 + I0 + i];
          sg = sp0g[bb * 4096 + 2048 + I0 + i];
        } else {
          su = spbuf[i][bb] + bcomb_lds[i];
          sg = spbuf[8 + i][bb] + bcomb_lds[8 + i];
        }
        float tu = b2f(tok_lds[0][bb][i]);
        float tg = b2f(tok_lds[1][bb][i]);
        float tv = b2f(tok_lds[2][bb][i]);
        float cand = tanhf(tu + su);
        float gate = 1.0f / (1.0f + expf(-(tg + sg)));
        float mix = gate * cand + (1.0f - gate) * tanhf(tv);
        nlbuf[bb][i] = f2bf(mix);
      }
      WAIT_LGKM0();  // nlbuf visible within wave 0 (lockstep, LDS drained)
      if (tid < 16) {  // publish slice via RETURNING atomic swap (performs at LLC)
        const int bb = tid >> 2, g = tid & 3;
        unsigned lo = nlbuf[bb][2 * g], hi = nlbuf[bb][2 * g + 1];
        unsigned* dst = (unsigned*)(mixedg + ((size_t)t * 4 + bb) * 2048 + I0);
        unsigned old = __hip_atomic_exchange(dst + g, lo | (hi << 16),
                                             __ATOMIC_RELAXED, __HIP_MEMORY_SCOPE_AGENT);
        asm volatile("" :: "v"(old));  // keep returning form live (sc0)
      }
      if (t < S_LEN - 1) {
        WAIT_VM0();  // swaps performed at LLC
        if (tid == 0)
          __hip_atomic_fetch_add(cnt, 1u, __ATOMIC_RELAXED, __HIP_MEMORY_SCOPE_AGENT);
        // wave 0 polls the single counter: all lanes same address -> one
        // coalesced line-read per block per round.
        const unsigned tgt = (unsigned)(t + 1) << 8;  // 256*(t+1)
        while (__hip_atomic_load(cnt, __ATOMIC_RELAXED, __HIP_MEMORY_SCOPE_AGENT) < tgt)
          __builtin_amdgcn_s_sleep(1);
      }
    }
    if (t < S_LEN - 1) __syncthreads();  // waves 1..3 released when wave 0 exits poll
  }
}

extern "C" void kernel_launch(void* const* d_in, const int* in_sizes, int n_in,
                              void* d_out, int out_size, void* d_ws, size_t ws_size,
                              hipStream_t stream) {
  (void)in_sizes; (void)n_in; (void)out_size; (void)ws_size;
  const float* hidden = (const float*)d_in[0];
  const float* state0 = (const float*)d_in[1];
  const float* w_in   = (const float*)d_in[2];
  const float* b_in   = (const float*)d_in[3];
  const float* w_sp   = (const float*)d_in[4];
  const float* b_sp   = (const float*)d_in[5];
  const float* w_out  = (const float*)d_in[6];
  const float* b_out  = (const float*)d_in[7];
  const float* w_up   = (const float*)d_in[8];
  const float* b_up   = (const float*)d_in[9];
  float* out = (float*)d_out;
  char* ws = (char*)d_ws;

  size_t o = 0;
  auto take = [&](size_t b) { size_t p = o; o += (b + 255) & ~(size_t)255; return p; };
  unsigned* cntp         = (unsigned*)(ws + take(256 * 4));
  float* sp0p            = (float*)(ws + take((size_t)4 * 4096 * 4));
  float* bcombp          = (float*)(ws + take((size_t)4096 * 4));
  unsigned short* hbf    = (unsigned short*)(ws + take((size_t)8192 * 1024 * 2));
  unsigned short* winbf  = (unsigned short*)(ws + take((size_t)6144 * 1024 * 2));
  unsigned short* wspbf  = (unsigned short*)(ws + take((size_t)4096 * 512 * 2));
  unsigned short* wupTbf = (unsigned short*)(ws + take((size_t)2048 * 512 * 2));
  unsigned short* woutbf = (unsigned short*)(ws + take((size_t)1024 * 2048 * 2));
  unsigned short* wcombbf= (unsigned short*)(ws + take((size_t)4096 * 2048 * 2));
  unsigned short* projbf = (unsigned short*)(ws + take((size_t)8192 * 6144 * 2));
  unsigned short* mixbf  = (unsigned short*)(ws + take((size_t)8192 * 2048 * 2));

  hipMemsetAsync(cntp, 0, 256 * 4, stream);

  conv_f32_bf16<<<4096, 256, 0, stream>>>(hidden, hbf, 1048576);
  conv_f32_bf16<<<3072, 256, 0, stream>>>(w_in, winbf, 786432);
  conv_f32_bf16<<<1024, 256, 0, stream>>>(w_sp, wspbf, 262144);
  conv_f32_bf16<<<1024, 256, 0, stream>>>(w_out, woutbf, 262144);
  transpose_wup<<<4096, 256, 0, stream>>>(w_up, wupTbf);

  // projected = hidden @ in_proj_w^T + b_in   [8192, 6144] bf16
  gemm_bt<0><<<dim3(64, 48), 256, 0, stream>>>(hbf, winbf, projbf, nullptr, b_in, 8192, 6144, 1024);
  // Wcomb = Wsp @ Wup   [4096, 2048] bf16  (B = Wup^T as [2048,512])
  gemm_bt<1><<<dim3(32, 16), 256, 0, stream>>>(wspbf, wupTbf, wcombbf, nullptr, nullptr, 4096, 2048, 512);

  bcomb_kernel<<<1024, 256, 0, stream>>>(w_sp, b_sp, b_up, bcombp);
  sp0_kernel<<<1024, 256, 0, stream>>>(w_sp, b_sp, state0, sp0p);

  {
    const unsigned short* a0 = wcombbf;
    const float* a1 = bcombp;
    const float* a2 = sp0p;
    const unsigned short* a3 = projbf;
    unsigned short* a4 = mixbf;
    unsigned* a5 = cntp;
    void* args[] = {&a0, &a1, &a2, &a3, &a4, &a5};
    hipLaunchCooperativeKernel((const void*)scan_kernel, dim3(NBLK), dim3(256), args, 0, stream);
  }

  // out = mixed @ out_proj_w^T + b_out  -> fp32, remapped to [B,S,D]
  gemm_bt<2><<<dim3(64, 8), 256, 0, stream>>>(mixbf, woutbf, nullptr, out, b_out, 8192, 1024, 2048);
  final_state_kernel<<<128, 256, 0, stream>>>(w_up, b_up, mixbf, out + (size_t)8192 * 1024);
}

// Round 6
// 15096.419 us; speedup vs baseline: 1.4648x; 1.2054x over previous
//
#include <hip/hip_runtime.h>
#include <hip/hip_bf16.h>

// Problem: B=4, S=2048, D=1024, INNER=2048, STATE=512.
// out = out_proj(scan(in_proj(hidden)));  scan folded via Wcomb = Wsp @ Wup.
// Round 6 = round-5 protocol (returning-swap publish + cumulative counter),
// scan restructured: single-wave blocks, MFMA dot, register token prefetch.

#define S_LEN 2048
#define NBATCH 4
#define NBLK 256

typedef __attribute__((ext_vector_type(4))) float f32x4;
typedef __attribute__((ext_vector_type(8))) short bf16x8;

__device__ __forceinline__ unsigned short f2bf(float f) {
  unsigned u = __builtin_bit_cast(unsigned, f);
  u += 0x7FFFu + ((u >> 16) & 1u);
  return (unsigned short)(u >> 16);
}
__device__ __forceinline__ float bflo(unsigned u) { return __builtin_bit_cast(float, (unsigned)(u << 16)); }
__device__ __forceinline__ float bfhi(unsigned u) { return __builtin_bit_cast(float, u & 0xFFFF0000u); }
__device__ __forceinline__ float b2f(unsigned short s) { return __builtin_bit_cast(float, (unsigned)s << 16); }

__device__ __forceinline__ float wave_sum64(float v) {
#pragma unroll
  for (int m = 32; m >= 1; m >>= 1) v += __shfl_xor(v, m, 64);
  return v;
}

#define WAIT_VM0()   asm volatile("s_waitcnt vmcnt(0)" ::: "memory")
#define WAIT_LGKM0() asm volatile("s_waitcnt lgkmcnt(0)" ::: "memory")

// ---------------- fp32 -> bf16 convert (8 elems/thread) ----------------
__global__ void conv_f32_bf16(const float* __restrict__ in, unsigned short* __restrict__ out, int n8) {
  int g = blockIdx.x * 256 + threadIdx.x;
  if (g >= n8) return;
  const float4* p = (const float4*)in + 2 * (size_t)g;
  float4 a = p[0], b = p[1];
  uint4 o;
  o.x = (unsigned)f2bf(a.x) | ((unsigned)f2bf(a.y) << 16);
  o.y = (unsigned)f2bf(a.z) | ((unsigned)f2bf(a.w) << 16);
  o.z = (unsigned)f2bf(b.x) | ((unsigned)f2bf(b.y) << 16);
  o.w = (unsigned)f2bf(b.z) | ((unsigned)f2bf(b.w) << 16);
  ((uint4*)out)[g] = o;
}

// ---------------- Wup [512][2048] -> WupT bf16 [2048][512] ----------------
__global__ void transpose_wup(const float* __restrict__ in, unsigned short* __restrict__ out) {
  int g = blockIdx.x * 256 + threadIdx.x; // over 2048*512
  int i = g >> 9, k = g & 511;
  out[g] = f2bf(in[(size_t)k * 2048 + i]);
}

// ---------------- b_comb[j] = b_sp[j] + sum_k Wsp[j,k]*b_up[k] ----------------
__global__ void bcomb_kernel(const float* __restrict__ wsp, const float* __restrict__ bsp,
                             const float* __restrict__ bup, float* __restrict__ bcomb) {
  int wv = (blockIdx.x * 256 + threadIdx.x) >> 6;
  int lane = threadIdx.x & 63;
  if (wv >= 4096) return;
  float s = 0.f;
  for (int k = lane; k < 512; k += 64) s += wsp[(size_t)wv * 512 + k] * bup[k];
  s = wave_sum64(s);
  if (lane == 0) bcomb[wv] = s + bsp[wv];
}

// ---------------- sp0[b][j] = b_sp[j] + sum_k state0[b,k]*Wsp[j,k] ----------------
__global__ void sp0_kernel(const float* __restrict__ wsp, const float* __restrict__ bsp,
                           const float* __restrict__ state0, float* __restrict__ sp0) {
  int wv = (blockIdx.x * 256 + threadIdx.x) >> 6;
  int lane = threadIdx.x & 63;
  if (wv >= 4096) return;
  float acc[NBATCH] = {0.f, 0.f, 0.f, 0.f};
  for (int k = lane; k < 512; k += 64) {
    float w = wsp[(size_t)wv * 512 + k];
#pragma unroll
    for (int bb = 0; bb < NBATCH; ++bb) acc[bb] += state0[bb * 512 + k] * w;
  }
#pragma unroll
  for (int bb = 0; bb < NBATCH; ++bb) acc[bb] = wave_sum64(acc[bb]);
  if (lane == 0) {
    float b = bsp[wv];
#pragma unroll
    for (int bb = 0; bb < NBATCH; ++bb) sp0[bb * 4096 + wv] = acc[bb] + b;
  }
}

// ---------------- final_state[b][j] = b_up[j] + sum_i mixed[2047,b,i]*Wup[j,i] ----------------
__global__ void final_state_kernel(const float* __restrict__ wup, const float* __restrict__ bup,
                                   const unsigned short* __restrict__ mixedg, float* __restrict__ dst) {
  int wv = (blockIdx.x * 256 + threadIdx.x) >> 6;
  int lane = threadIdx.x & 63;
  if (wv >= 512) return;
  float acc[NBATCH] = {0.f, 0.f, 0.f, 0.f};
  for (int i = lane; i < 2048; i += 64) {
    float w = wup[(size_t)wv * 2048 + i];
#pragma unroll
    for (int bb = 0; bb < NBATCH; ++bb)
      acc[bb] += b2f(mixedg[((size_t)2047 * 4 + bb) * 2048 + i]) * w;
  }
#pragma unroll
  for (int bb = 0; bb < NBATCH; ++bb) acc[bb] = wave_sum64(acc[bb]);
  if (lane == 0) {
    float b = bup[wv];
#pragma unroll
    for (int bb = 0; bb < NBATCH; ++bb) dst[bb * 512 + wv] = acc[bb] + b;
  }
}

// ---------------- bf16 BT-GEMM: C[M,N] = A[M,K] @ B[N,K]^T (+bias) ----------------
// MODE 0: bf16 out + bias; MODE 1: bf16 out, no bias; MODE 2: fp32 out, bias,
// row remap m=s*4+b -> out[b][s][n] (S=2048, N=1024 hardcoded for out_proj).
template <int MODE>
__global__ __launch_bounds__(256) void gemm_bt(
    const unsigned short* __restrict__ A, const unsigned short* __restrict__ B,
    unsigned short* __restrict__ Cbf, float* __restrict__ Cf32,
    const float* __restrict__ bias, int M, int N, int K) {
  const int tm = blockIdx.x * 128, tn = blockIdx.y * 128;
  __shared__ __align__(16) unsigned short At[128][72];
  __shared__ __align__(16) unsigned short Bt[128][72];
  const int tid = threadIdx.x, lane = tid & 63, w = tid >> 6;
  const int wm = (w >> 1) * 64, wn = (w & 1) * 64;
  f32x4 acc[4][4];
#pragma unroll
  for (int a = 0; a < 4; ++a)
#pragma unroll
    for (int b = 0; b < 4; ++b) acc[a][b] = (f32x4)0.f;

  for (int k0 = 0; k0 < K; k0 += 64) {
#pragma unroll
    for (int it = 0; it < 4; ++it) {
      int c = tid + it * 256;
      int r = c >> 3, kp = (c & 7) * 8;
      *(uint4*)&At[r][kp] = *(const uint4*)&A[(size_t)(tm + r) * K + k0 + kp];
      *(uint4*)&Bt[r][kp] = *(const uint4*)&B[(size_t)(tn + r) * K + k0 + kp];
    }
    __syncthreads();
#pragma unroll
    for (int kk = 0; kk < 2; ++kk) {
      bf16x8 af[4], bfr[4];
#pragma unroll
      for (int fm = 0; fm < 4; ++fm)
        af[fm] = *(const bf16x8*)&At[wm + fm * 16 + (lane & 15)][(kk << 5) + ((lane >> 4) << 3)];
#pragma unroll
      for (int fn = 0; fn < 4; ++fn)
        bfr[fn] = *(const bf16x8*)&Bt[wn + fn * 16 + (lane & 15)][(kk << 5) + ((lane >> 4) << 3)];
#pragma unroll
      for (int fm = 0; fm < 4; ++fm)
#pragma unroll
        for (int fn = 0; fn < 4; ++fn)
          acc[fm][fn] = __builtin_amdgcn_mfma_f32_16x16x32_bf16(af[fm], bfr[fn], acc[fm][fn], 0, 0, 0);
    }
    __syncthreads();
  }
  // epilogue
  float bv[4];
#pragma unroll
  for (int fn = 0; fn < 4; ++fn) {
    if constexpr (MODE != 1) bv[fn] = bias[tn + wn + fn * 16 + (lane & 15)];
    else bv[fn] = 0.f;
  }
#pragma unroll
  for (int fm = 0; fm < 4; ++fm)
#pragma unroll
    for (int fn = 0; fn < 4; ++fn)
#pragma unroll
      for (int r = 0; r < 4; ++r) {
        int row = tm + wm + fm * 16 + ((lane >> 4) << 2) + r;
        int col = tn + wn + fn * 16 + (lane & 15);
        float v = acc[fm][fn][r] + bv[fn];
        if constexpr (MODE == 2) {
          Cf32[(size_t)(((row & 3) << 11) + (row >> 2)) * 1024 + col] = v;
        } else {
          Cbf[(size_t)row * N + col] = f2bf(v);
        }
      }
}

// ---------------- persistent scan kernel (single wave per block) ----------------
// 256 blocks x 64 threads, 1 block/CU. Block b owns INNER slice [8b, 8b+8).
// Per step: stage mixed_{t-1} (16 KB, plain loads), MFMA dot
// D[j,bb] = sum_k Wcomb[j,k]*mixed[bb,k]  (one 16x16x32 chain, K=2048),
// nonlinearity (lanes 0-31, tokens pre-fetched into registers last step),
// publish via RETURNING atomic swaps, vmcnt drain, counter add, poll.
__global__ __launch_bounds__(64, 1) void scan_kernel(
    const unsigned short* __restrict__ wcombg,  // [4096][2048] bf16
    const float* __restrict__ bcombg,           // [4096]
    const float* __restrict__ sp0g,             // [4][4096]
    const unsigned short* __restrict__ projg,   // [8192][6144] bf16, m=b*2048+s
    unsigned short* __restrict__ mixedg,        // [2048][4][2048] bf16
    unsigned int* __restrict__ cnt)             // [1], zeroed before launch
{
  __shared__ __align__(16) unsigned short wcomb_lds[16][2048];  // 64 KB
  __shared__ __align__(16) unsigned short mixed_lds[5][2048];   // 20 KB, row4 = zeros
  __shared__ __align__(16) float spbuf[16][4];
  __shared__ __align__(16) float bcomb_lds[16];
  __shared__ __align__(16) unsigned short nlbuf[4][8];

  const int lane = threadIdx.x, bid = blockIdx.x;
  const int I0 = bid * 8;
  const int col = lane & 15;            // MFMA row/col index
  const int krow = (lane >> 4) << 3;    // MFMA k-subgroup offset

  // ---- prologue: stage Wcomb slice (u rows I0.., g rows 2048+I0..) ----
  for (int c = lane; c < 4096; c += 64) {
    int r = c >> 8, kp = (c & 255) << 3;
    int gj = (r < 8) ? (I0 + r) : (2048 + I0 + r - 8);
    *(uint4*)&wcomb_lds[r][kp] = *(const uint4*)&wcombg[((size_t)gj << 11) + kp];
  }
  // zero pad row (B-fragment source for unused MFMA cols 4..15)
  for (int c = lane; c < 256; c += 64) {
    uint4 z; z.x = 0; z.y = 0; z.z = 0; z.w = 0;
    ((uint4*)&mixed_lds[4][0])[c] = z;
  }
  if (lane < 16) bcomb_lds[lane] = bcombg[(lane < 8) ? (I0 + lane) : (2048 + I0 + lane - 8)];

  // ---- prologue: t=0 tokens + sp0 into registers (lanes 0..31) ----
  unsigned short rtu = 0, rtg = 0, rtv = 0;
  float su0 = 0.f, sg0 = 0.f;
  if (lane < 32) {
    const int i = lane & 7, bb = lane >> 3;
    size_t base = (size_t)(bb * 2048) * 6144 + I0 + i;
    rtu = projg[base];
    rtg = projg[base + 2048];
    rtv = projg[base + 4096];
    su0 = sp0g[bb * 4096 + I0 + i];
    sg0 = sp0g[bb * 4096 + 2048 + I0 + i];
  }
  WAIT_LGKM0();

  const unsigned short* arow = &wcomb_lds[col][0];
  const unsigned short* brow = &mixed_lds[(col < 4) ? col : 4][0];

#pragma unroll 1
  for (int t = 0; t < S_LEN; ++t) {
    float su = su0, sg = sg0;
    if (t > 0) {
      // ---- stage mixed_{t-1} (16 KB): 16 x uint4 per lane, plain loads ----
      {
        const uint4* src = (const uint4*)(mixedg + ((size_t)(t - 1) << 13));
        uint4* dst = (uint4*)&mixed_lds[0][0];
#pragma unroll
        for (int c = 0; c < 16; ++c) dst[lane + (c << 6)] = src[lane + (c << 6)];
      }
      WAIT_LGKM0();  // LDS writes complete (same wave)

      // ---- MFMA dot: D[j, bb] = sum_k W[j,k] * mx[bb,k] ----
      f32x4 acc = (f32x4)0.f;
#pragma unroll 4
      for (int k0 = 0; k0 < 2048; k0 += 32) {
        bf16x8 a = *(const bf16x8*)&arow[k0 + krow];
        bf16x8 b = *(const bf16x8*)&brow[k0 + krow];
        acc = __builtin_amdgcn_mfma_f32_16x16x32_bf16(a, b, acc, 0, 0, 0);
      }
      if (col < 4) {
#pragma unroll
        for (int r = 0; r < 4; ++r) spbuf[((lane >> 4) << 2) + r][col] = acc[r];
      }
      WAIT_LGKM0();  // spbuf visible within wave
      if (lane < 32) {
        const int i = lane & 7, bb = lane >> 3;
        su = spbuf[i][bb] + bcomb_lds[i];
        sg = spbuf[8 + i][bb] + bcomb_lds[8 + i];
      }
    }

    // ---- nonlinearity (lanes 0..31), tokens from registers ----
    if (lane < 32) {
      float tu = b2f(rtu), tg = b2f(rtg), tv = b2f(rtv);
      float cand = tanhf(tu + su);
      float gate = 1.0f / (1.0f + expf(-(tg + sg)));
      float mix = gate * cand + (1.0f - gate) * tanhf(tv);
      nlbuf[lane >> 3][lane & 7] = f2bf(mix);
    }
    WAIT_LGKM0();  // nlbuf visible within wave

    // ---- publish slice via RETURNING atomic swaps (performed at LLC) ----
    if (lane < 16) {
      const int bb = lane >> 2, g = lane & 3;
      unsigned lo = nlbuf[bb][2 * g], hi = nlbuf[bb][2 * g + 1];
      unsigned* dst = (unsigned*)(mixedg + ((size_t)t * 4 + bb) * 2048 + I0);
      unsigned old = __hip_atomic_exchange(dst + g, lo | (hi << 16),
                                           __ATOMIC_RELAXED, __HIP_MEMORY_SCOPE_AGENT);
      asm volatile("" :: "v"(old));  // keep returning form live (sc0)
    }

    if (t < S_LEN - 1) {
      WAIT_VM0();  // swaps performed at LLC
      if (lane == 0)
        __hip_atomic_fetch_add(cnt, 1u, __ATOMIC_RELAXED, __HIP_MEMORY_SCOPE_AGENT);
      // ---- token prefetch for step t+1 (hidden under poll + stage + dot) ----
      if (lane < 32) {
        const int i = lane & 7, bb = lane >> 3;
        size_t base = (size_t)(bb * 2048 + t + 1) * 6144 + I0 + i;
        rtu = projg[base];
        rtg = projg[base + 2048];
        rtv = projg[base + 4096];
      }
      // ---- poll single cumulative counter ----
      const unsigned tgt = (unsigned)(t + 1) << 8;  // 256*(t+1)
      while (__hip_atomic_load(cnt, __ATOMIC_RELAXED, __HIP_MEMORY_SCOPE_AGENT) < tgt)
        __builtin_amdgcn_s_sleep(1);
    }
  }
}

extern "C" void kernel_launch(void* const* d_in, const int* in_sizes, int n_in,
                              void* d_out, int out_size, void* d_ws, size_t ws_size,
                              hipStream_t stream) {
  (void)in_sizes; (void)n_in; (void)out_size; (void)ws_size;
  const float* hidden = (const float*)d_in[0];
  const float* state0 = (const float*)d_in[1];
  const float* w_in   = (const float*)d_in[2];
  const float* b_in   = (const float*)d_in[3];
  const float* w_sp   = (const float*)d_in[4];
  const float* b_sp   = (const float*)d_in[5];
  const float* w_out  = (const float*)d_in[6];
  const float* b_out  = (const float*)d_in[7];
  const float* w_up   = (const float*)d_in[8];
  const float* b_up   = (const float*)d_in[9];
  float* out = (float*)d_out;
  char* ws = (char*)d_ws;

  size_t o = 0;
  auto take = [&](size_t b) { size_t p = o; o += (b + 255) & ~(size_t)255; return p; };
  unsigned* cntp         = (unsigned*)(ws + take(256 * 4));
  float* sp0p            = (float*)(ws + take((size_t)4 * 4096 * 4));
  float* bcombp          = (float*)(ws + take((size_t)4096 * 4));
  unsigned short* hbf    = (unsigned short*)(ws + take((size_t)8192 * 1024 * 2));
  unsigned short* winbf  = (unsigned short*)(ws + take((size_t)6144 * 1024 * 2));
  unsigned short* wspbf  = (unsigned short*)(ws + take((size_t)4096 * 512 * 2));
  unsigned short* wupTbf = (unsigned short*)(ws + take((size_t)2048 * 512 * 2));
  unsigned short* woutbf = (unsigned short*)(ws + take((size_t)1024 * 2048 * 2));
  unsigned short* wcombbf= (unsigned short*)(ws + take((size_t)4096 * 2048 * 2));
  unsigned short* projbf = (unsigned short*)(ws + take((size_t)8192 * 6144 * 2));
  unsigned short* mixbf  = (unsigned short*)(ws + take((size_t)8192 * 2048 * 2));

  hipMemsetAsync(cntp, 0, 256 * 4, stream);

  conv_f32_bf16<<<4096, 256, 0, stream>>>(hidden, hbf, 1048576);
  conv_f32_bf16<<<3072, 256, 0, stream>>>(w_in, winbf, 786432);
  conv_f32_bf16<<<1024, 256, 0, stream>>>(w_sp, wspbf, 262144);
  conv_f32_bf16<<<1024, 256, 0, stream>>>(w_out, woutbf, 262144);
  transpose_wup<<<4096, 256, 0, stream>>>(w_up, wupTbf);

  // projected = hidden @ in_proj_w^T + b_in   [8192, 6144] bf16
  gemm_bt<0><<<dim3(64, 48), 256, 0, stream>>>(hbf, winbf, projbf, nullptr, b_in, 8192, 6144, 1024);
  // Wcomb = Wsp @ Wup   [4096, 2048] bf16  (B = Wup^T as [2048,512])
  gemm_bt<1><<<dim3(32, 16), 256, 0, stream>>>(wspbf, wupTbf, wcombbf, nullptr, nullptr, 4096, 2048, 512);

  bcomb_kernel<<<1024, 256, 0, stream>>>(w_sp, b_sp, b_up, bcombp);
  sp0_kernel<<<1024, 256, 0, stream>>>(w_sp, b_sp, state0, sp0p);

  {
    const unsigned short* a0 = wcombbf;
    const float* a1 = bcombp;
    const float* a2 = sp0p;
    const unsigned short* a3 = projbf;
    unsigned short* a4 = mixbf;
    unsigned* a5 = cntp;
    void* args[] = {&a0, &a1, &a2, &a3, &a4, &a5};
    hipLaunchCooperativeKernel((const void*)scan_kernel, dim3(NBLK), dim3(64), args, 0, stream);
  }

  // out = mixed @ out_proj_w^T + b_out  -> fp32, remapped to [B,S,D]
  gemm_bt<2><<<dim3(64, 8), 256, 0, stream>>>(mixbf, woutbf, nullptr, out, b_out, 8192, 1024, 2048);
  final_state_kernel<<<128, 256, 0, stream>>>(w_up, b_up, mixbf, out + (size_t)8192 * 1024);
}

// Round 9
// 13893.683 us; speedup vs baseline: 1.5916x; 1.0866x over previous
//
#include <hip/hip_runtime.h>
#include <hip/hip_bf16.h>

// Problem: B=4, S=2048, D=1024, INNER=2048, STATE=512.
// out = out_proj(scan(in_proj(hidden)));  scan folded via Wcomb = Wsp @ Wup.
// Round 9 = round-6 (PASS, 15.1ms) + ONE change: LDS tiles padded to stride
// 2056 bf16 (4112 B, 16B-aligned, bank shift 4/row) -> A-reads 16-way->2-way
// (free), B-reads conflict-free. Instruction stream otherwise identical.
// History: r2/r3/r7/r8 all failed with IDENTICAL absmax (scan contributed
// nothing); r8 refuted the gld16 theory. Bisect from passing lineage only.

#define S_LEN 2048
#define NBATCH 4
#define NBLK 256
#define LSTR 2056  // padded LDS row stride in bf16 (4112 B, 16B-aligned)

typedef __attribute__((ext_vector_type(4))) float f32x4;
typedef __attribute__((ext_vector_type(8))) short bf16x8;

__device__ __forceinline__ unsigned short f2bf(float f) {
  unsigned u = __builtin_bit_cast(unsigned, f);
  u += 0x7FFFu + ((u >> 16) & 1u);
  return (unsigned short)(u >> 16);
}
__device__ __forceinline__ float b2f(unsigned short s) { return __builtin_bit_cast(float, (unsigned)s << 16); }

__device__ __forceinline__ float wave_sum64(float v) {
#pragma unroll
  for (int m = 32; m >= 1; m >>= 1) v += __shfl_xor(v, m, 64);
  return v;
}

#define WAIT_VM0()   asm volatile("s_waitcnt vmcnt(0)" ::: "memory")
#define WAIT_LGKM0() asm volatile("s_waitcnt lgkmcnt(0)" ::: "memory")

// ---------------- fp32 -> bf16 convert (8 elems/thread) ----------------
__global__ void conv_f32_bf16(const float* __restrict__ in, unsigned short* __restrict__ out, int n8) {
  int g = blockIdx.x * 256 + threadIdx.x;
  if (g >= n8) return;
  const float4* p = (const float4*)in + 2 * (size_t)g;
  float4 a = p[0], b = p[1];
  uint4 o;
  o.x = (unsigned)f2bf(a.x) | ((unsigned)f2bf(a.y) << 16);
  o.y = (unsigned)f2bf(a.z) | ((unsigned)f2bf(a.w) << 16);
  o.z = (unsigned)f2bf(b.x) | ((unsigned)f2bf(b.y) << 16);
  o.w = (unsigned)f2bf(b.z) | ((unsigned)f2bf(b.w) << 16);
  ((uint4*)out)[g] = o;
}

// ---------------- Wup [512][2048] -> WupT bf16 [2048][512] ----------------
__global__ void transpose_wup(const float* __restrict__ in, unsigned short* __restrict__ out) {
  int g = blockIdx.x * 256 + threadIdx.x; // over 2048*512
  int i = g >> 9, k = g & 511;
  out[g] = f2bf(in[(size_t)k * 2048 + i]);
}

// ---------------- b_comb[j] = b_sp[j] + sum_k Wsp[j,k]*b_up[k] ----------------
__global__ void bcomb_kernel(const float* __restrict__ wsp, const float* __restrict__ bsp,
                             const float* __restrict__ bup, float* __restrict__ bcomb) {
  int wv = (blockIdx.x * 256 + threadIdx.x) >> 6;
  int lane = threadIdx.x & 63;
  if (wv >= 4096) return;
  float s = 0.f;
  for (int k = lane; k < 512; k += 64) s += wsp[(size_t)wv * 512 + k] * bup[k];
  s = wave_sum64(s);
  if (lane == 0) bcomb[wv] = s + bsp[wv];
}

// ---------------- sp0[b][j] = b_sp[j] + sum_k state0[b,k]*Wsp[j,k] ----------------
__global__ void sp0_kernel(const float* __restrict__ wsp, const float* __restrict__ bsp,
                           const float* __restrict__ state0, float* __restrict__ sp0) {
  int wv = (blockIdx.x * 256 + threadIdx.x) >> 6;
  int lane = threadIdx.x & 63;
  if (wv >= 4096) return;
  float acc[NBATCH] = {0.f, 0.f, 0.f, 0.f};
  for (int k = lane; k < 512; k += 64) {
    float w = wsp[(size_t)wv * 512 + k];
#pragma unroll
    for (int bb = 0; bb < NBATCH; ++bb) acc[bb] += state0[bb * 512 + k] * w;
  }
#pragma unroll
  for (int bb = 0; bb < NBATCH; ++bb) acc[bb] = wave_sum64(acc[bb]);
  if (lane == 0) {
    float b = bsp[wv];
#pragma unroll
    for (int bb = 0; bb < NBATCH; ++bb) sp0[bb * 4096 + wv] = acc[bb] + b;
  }
}

// ---------------- final_state[b][j] = b_up[j] + sum_i mixed[2047,b,i]*Wup[j,i] ----------------
__global__ void final_state_kernel(const float* __restrict__ wup, const float* __restrict__ bup,
                                   const unsigned short* __restrict__ mixedg, float* __restrict__ dst) {
  int wv = (blockIdx.x * 256 + threadIdx.x) >> 6;
  int lane = threadIdx.x & 63;
  if (wv >= 512) return;
  float acc[NBATCH] = {0.f, 0.f, 0.f, 0.f};
  for (int i = lane; i < 2048; i += 64) {
    float w = wup[(size_t)wv * 2048 + i];
#pragma unroll
    for (int bb = 0; bb < NBATCH; ++bb)
      acc[bb] += b2f(mixedg[((size_t)2047 * 4 + bb) * 2048 + i]) * w;
  }
#pragma unroll
  for (int bb = 0; bb < NBATCH; ++bb) acc[bb] = wave_sum64(acc[bb]);
  if (lane == 0) {
    float b = bup[wv];
#pragma unroll
    for (int bb = 0; bb < NBATCH; ++bb) dst[bb * 512 + wv] = acc[bb] + b;
  }
}

// ---------------- bf16 BT-GEMM: C[M,N] = A[M,K] @ B[N,K]^T (+bias) ----------------
// MODE 0: bf16 out + bias; MODE 1: bf16 out, no bias; MODE 2: fp32 out, bias,
// row remap m=s*4+b -> out[b][s][n] (S=2048, N=1024 hardcoded for out_proj).
template <int MODE>
__global__ __launch_bounds__(256) void gemm_bt(
    const unsigned short* __restrict__ A, const unsigned short* __restrict__ B,
    unsigned short* __restrict__ Cbf, float* __restrict__ Cf32,
    const float* __restrict__ bias, int M, int N, int K) {
  const int tm = blockIdx.x * 128, tn = blockIdx.y * 128;
  __shared__ __align__(16) unsigned short At[128][72];
  __shared__ __align__(16) unsigned short Bt[128][72];
  const int tid = threadIdx.x, lane = tid & 63, w = tid >> 6;
  const int wm = (w >> 1) * 64, wn = (w & 1) * 64;
  f32x4 acc[4][4];
#pragma unroll
  for (int a = 0; a < 4; ++a)
#pragma unroll
    for (int b = 0; b < 4; ++b) acc[a][b] = (f32x4)0.f;

  for (int k0 = 0; k0 < K; k0 += 64) {
#pragma unroll
    for (int it = 0; it < 4; ++it) {
      int c = tid + it * 256;
      int r = c >> 3, kp = (c & 7) * 8;
      *(uint4*)&At[r][kp] = *(const uint4*)&A[(size_t)(tm + r) * K + k0 + kp];
      *(uint4*)&Bt[r][kp] = *(const uint4*)&B[(size_t)(tn + r) * K + k0 + kp];
    }
    __syncthreads();
#pragma unroll
    for (int kk = 0; kk < 2; ++kk) {
      bf16x8 af[4], bfr[4];
#pragma unroll
      for (int fm = 0; fm < 4; ++fm)
        af[fm] = *(const bf16x8*)&At[wm + fm * 16 + (lane & 15)][(kk << 5) + ((lane >> 4) << 3)];
#pragma unroll
      for (int fn = 0; fn < 4; ++fn)
        bfr[fn] = *(const bf16x8*)&Bt[wn + fn * 16 + (lane & 15)][(kk << 5) + ((lane >> 4) << 3)];
#pragma unroll
      for (int fm = 0; fm < 4; ++fm)
#pragma unroll
        for (int fn = 0; fn < 4; ++fn)
          acc[fm][fn] = __builtin_amdgcn_mfma_f32_16x16x32_bf16(af[fm], bfr[fn], acc[fm][fn], 0, 0, 0);
    }
    __syncthreads();
  }
  // epilogue
  float bv[4];
#pragma unroll
  for (int fn = 0; fn < 4; ++fn) {
    if constexpr (MODE != 1) bv[fn] = bias[tn + wn + fn * 16 + (lane & 15)];
    else bv[fn] = 0.f;
  }
#pragma unroll
  for (int fm = 0; fm < 4; ++fm)
#pragma unroll
    for (int fn = 0; fn < 4; ++fn)
#pragma unroll
      for (int r = 0; r < 4; ++r) {
        int row = tm + wm + fm * 16 + ((lane >> 4) << 2) + r;
        int col = tn + wn + fn * 16 + (lane & 15);
        float v = acc[fm][fn][r] + bv[fn];
        if constexpr (MODE == 2) {
          Cf32[(size_t)(((row & 3) << 11) + (row >> 2)) * 1024 + col] = v;
        } else {
          Cbf[(size_t)row * N + col] = f2bf(v);
        }
      }
}

// ---------------- persistent scan kernel (single wave per block) ----------------
// 256 blocks x 64 threads, 1 block/CU. Block b owns INNER slice [8b, 8b+8).
// Per step: stage mixed_{t-1} (16 KB, plain loads -> PADDED LDS), MFMA dot
// D[j,bb] = sum_k Wcomb[j,k]*mixed[bb,k] (one 16x16x32 chain, K=2048),
// nonlinearity (lanes 0-31, tokens pre-fetched into registers last step),
// publish via RETURNING atomic swaps, vmcnt drain, counter add, poll.
__global__ __launch_bounds__(64, 1) void scan_kernel(
    const unsigned short* __restrict__ wcombg,  // [4096][2048] bf16
    const float* __restrict__ bcombg,           // [4096]
    const float* __restrict__ sp0g,             // [4][4096]
    const unsigned short* __restrict__ projg,   // [8192][6144] bf16, m=b*2048+s
    unsigned short* __restrict__ mixedg,        // [2048][4][2048] bf16
    unsigned int* __restrict__ cnt)             // [1], zeroed before launch
{
  // Padded tiles: stride 2056 bf16 = 4112 B (16B-aligned), bank shift 4/row.
  // wcomb reads: rows r and r+8 share a bank (2 addrs = 2-way = free, m136).
  // mixed reads: rows 0..4 on distinct banks -> conflict-free.
  __shared__ __align__(16) unsigned short wcomb_lds[16][LSTR];  // 65.8 KB
  __shared__ __align__(16) unsigned short mixed_lds[5][LSTR];   // 20.6 KB, row4 = zeros
  __shared__ __align__(16) float spbuf[16][4];
  __shared__ __align__(16) float bcomb_lds[16];
  __shared__ __align__(16) unsigned short nlbuf[4][8];

  const int lane = threadIdx.x, bid = blockIdx.x;
  const int I0 = bid * 8;
  const int col = lane & 15;            // MFMA row/col index
  const int krow = (lane >> 4) << 3;    // MFMA k-subgroup offset

  // ---- prologue: stage Wcomb slice (u rows I0.., g rows 2048+I0..) ----
  for (int c = lane; c < 4096; c += 64) {
    int r = c >> 8, kp = (c & 255) << 3;
    int gj = (r < 8) ? (I0 + r) : (2048 + I0 + r - 8);
    *(uint4*)&wcomb_lds[r][kp] = *(const uint4*)&wcombg[((size_t)gj << 11) + kp];
  }
  // zero pad row (B-fragment source for unused MFMA cols 4..15)
  for (int c = lane; c < 256; c += 64) {
    uint4 z; z.x = 0; z.y = 0; z.z = 0; z.w = 0;
    ((uint4*)&mixed_lds[4][0])[c] = z;
  }
  if (lane < 16) bcomb_lds[lane] = bcombg[(lane < 8) ? (I0 + lane) : (2048 + I0 + lane - 8)];

  // ---- prologue: t=0 tokens + sp0 into registers (lanes 0..31) ----
  unsigned short rtu = 0, rtg = 0, rtv = 0;
  float su0 = 0.f, sg0 = 0.f;
  if (lane < 32) {
    const int i = lane & 7, bb = lane >> 3;
    size_t base = (size_t)(bb * 2048) * 6144 + I0 + i;
    rtu = projg[base];
    rtg = projg[base + 2048];
    rtv = projg[base + 4096];
    su0 = sp0g[bb * 4096 + I0 + i];
    sg0 = sp0g[bb * 4096 + 2048 + I0 + i];
  }
  WAIT_LGKM0();

  const unsigned short* arow = &wcomb_lds[col][0];
  const unsigned short* brow = &mixed_lds[(col < 4) ? col : 4][0];

#pragma unroll 1
  for (int t = 0; t < S_LEN; ++t) {
    float su = su0, sg = sg0;
    if (t > 0) {
      // ---- stage mixed_{t-1} (16 KB): plain loads -> padded LDS ----
      {
        const uint4* src = (const uint4*)(mixedg + ((size_t)(t - 1) << 13));
#pragma unroll
        for (int c = 0; c < 16; ++c) {
          int u = lane + (c << 6);               // uint4 index 0..1023
          uint4 v = src[u];
          *(uint4*)&mixed_lds[u >> 8][(u & 255) << 3] = v;   // 256 uint4/row
        }
      }
      WAIT_LGKM0();  // LDS writes complete (same wave)

      // ---- MFMA dot: D[j, bb] = sum_k W[j,k] * mx[bb,k] ----
      f32x4 acc = (f32x4)0.f;
#pragma unroll 4
      for (int k0 = 0; k0 < 2048; k0 += 32) {
        bf16x8 a = *(const bf16x8*)&arow[k0 + krow];
        bf16x8 b = *(const bf16x8*)&brow[k0 + krow];
        acc = __builtin_amdgcn_mfma_f32_16x16x32_bf16(a, b, acc, 0, 0, 0);
      }
      if (col < 4) {
#pragma unroll
        for (int r = 0; r < 4; ++r) spbuf[((lane >> 4) << 2) + r][col] = acc[r];
      }
      WAIT_LGKM0();  // spbuf visible within wave
      if (lane < 32) {
        const int i = lane & 7, bb = lane >> 3;
        su = spbuf[i][bb] + bcomb_lds[i];
        sg = spbuf[8 + i][bb] + bcomb_lds[8 + i];
      }
    }

    // ---- nonlinearity (lanes 0..31), tokens from registers ----
    if (lane < 32) {
      float tu = b2f(rtu), tg = b2f(rtg), tv = b2f(rtv);
      float cand = tanhf(tu + su);
      float gate = 1.0f / (1.0f + expf(-(tg + sg)));
      float mix = gate * cand + (1.0f - gate) * tanhf(tv);
      nlbuf[lane >> 3][lane & 7] = f2bf(mix);
    }
    WAIT_LGKM0();  // nlbuf visible within wave

    // ---- publish slice via RETURNING atomic swaps (performed at LLC) ----
    if (lane < 16) {
      const int bb = lane >> 2, g = lane & 3;
      unsigned lo = nlbuf[bb][2 * g], hi = nlbuf[bb][2 * g + 1];
      unsigned* dst = (unsigned*)(mixedg + ((size_t)t * 4 + bb) * 2048 + I0);
      unsigned old = __hip_atomic_exchange(dst + g, lo | (hi << 16),
                                           __ATOMIC_RELAXED, __HIP_MEMORY_SCOPE_AGENT);
      asm volatile("" :: "v"(old));  // keep returning form live (sc0)
    }

    if (t < S_LEN - 1) {
      WAIT_VM0();  // swaps performed at LLC
      if (lane == 0)
        __hip_atomic_fetch_add(cnt, 1u, __ATOMIC_RELAXED, __HIP_MEMORY_SCOPE_AGENT);
      // ---- token prefetch for step t+1 (hidden under poll + stage + dot) ----
      if (lane < 32) {
        const int i = lane & 7, bb = lane >> 3;
        size_t base = (size_t)(bb * 2048 + t + 1) * 6144 + I0 + i;
        rtu = projg[base];
        rtg = projg[base + 2048];
        rtv = projg[base + 4096];
      }
      // ---- poll single cumulative counter ----
      const unsigned tgt = (unsigned)(t + 1) << 8;  // 256*(t+1)
      while (__hip_atomic_load(cnt, __ATOMIC_RELAXED, __HIP_MEMORY_SCOPE_AGENT) < tgt)
        __builtin_amdgcn_s_sleep(1);
    }
  }
}

extern "C" void kernel_launch(void* const* d_in, const int* in_sizes, int n_in,
                              void* d_out, int out_size, void* d_ws, size_t ws_size,
                              hipStream_t stream) {
  (void)in_sizes; (void)n_in; (void)out_size; (void)ws_size;
  const float* hidden = (const float*)d_in[0];
  const float* state0 = (const float*)d_in[1];
  const float* w_in   = (const float*)d_in[2];
  const float* b_in   = (const float*)d_in[3];
  const float* w_sp   = (const float*)d_in[4];
  const float* b_sp   = (const float*)d_in[5];
  const float* w_out  = (const float*)d_in[6];
  const float* b_out  = (const float*)d_in[7];
  const float* w_up   = (const float*)d_in[8];
  const float* b_up   = (const float*)d_in[9];
  float* out = (float*)d_out;
  char* ws = (char*)d_ws;

  size_t o = 0;
  auto take = [&](size_t b) { size_t p = o; o += (b + 255) & ~(size_t)255; return p; };
  unsigned* cntp         = (unsigned*)(ws + take(256 * 4));
  float* sp0p            = (float*)(ws + take((size_t)4 * 4096 * 4));
  float* bcombp          = (float*)(ws + take((size_t)4096 * 4));
  unsigned short* hbf    = (unsigned short*)(ws + take((size_t)8192 * 1024 * 2));
  unsigned short* winbf  = (unsigned short*)(ws + take((size_t)6144 * 1024 * 2));
  unsigned short* wspbf  = (unsigned short*)(ws + take((size_t)4096 * 512 * 2));
  unsigned short* wupTbf = (unsigned short*)(ws + take((size_t)2048 * 512 * 2));
  unsigned short* woutbf = (unsigned short*)(ws + take((size_t)1024 * 2048 * 2));
  unsigned short* wcombbf= (unsigned short*)(ws + take((size_t)4096 * 2048 * 2));
  unsigned short* projbf = (unsigned short*)(ws + take((size_t)8192 * 6144 * 2));
  unsigned short* mixbf  = (unsigned short*)(ws + take((size_t)8192 * 2048 * 2));

  hipMemsetAsync(cntp, 0, 256 * 4, stream);

  conv_f32_bf16<<<4096, 256, 0, stream>>>(hidden, hbf, 1048576);
  conv_f32_bf16<<<3072, 256, 0, stream>>>(w_in, winbf, 786432);
  conv_f32_bf16<<<1024, 256, 0, stream>>>(w_sp, wspbf, 262144);
  conv_f32_bf16<<<1024, 256, 0, stream>>>(w_out, woutbf, 262144);
  transpose_wup<<<4096, 256, 0, stream>>>(w_up, wupTbf);

  // projected = hidden @ in_proj_w^T + b_in   [8192, 6144] bf16
  gemm_bt<0><<<dim3(64, 48), 256, 0, stream>>>(hbf, winbf, projbf, nullptr, b_in, 8192, 6144, 1024);
  // Wcomb = Wsp @ Wup   [4096, 2048] bf16  (B = Wup^T as [2048,512])
  gemm_bt<1><<<dim3(32, 16), 256, 0, stream>>>(wspbf, wupTbf, wcombbf, nullptr, nullptr, 4096, 2048, 512);

  bcomb_kernel<<<1024, 256, 0, stream>>>(w_sp, b_sp, b_up, bcombp);
  sp0_kernel<<<1024, 256, 0, stream>>>(w_sp, b_sp, state0, sp0p);

  {
    const unsigned short* a0 = wcombbf;
    const float* a1 = bcombp;
    const float* a2 = sp0p;
    const unsigned short* a3 = projbf;
    unsigned short* a4 = mixbf;
    unsigned* a5 = cntp;
    void* args[] = {&a0, &a1, &a2, &a3, &a4, &a5};
    hipLaunchCooperativeKernel((const void*)scan_kernel, dim3(NBLK), dim3(64), args, 0, stream);
  }

  // out = mixed @ out_proj_w^T + b_out  -> fp32, remapped to [B,S,D]
  gemm_bt<2><<<dim3(64, 8), 256, 0, stream>>>(mixbf, woutbf, nullptr, out, b_out, 8192, 1024, 2048);
  final_state_kernel<<<128, 256, 0, stream>>>(w_up, b_up, mixbf, out + (size_t)8192 * 1024);
}